// Round 2
// baseline (528.294 us; speedup 1.0000x reference)
//
#include <hip/hip_runtime.h>

typedef unsigned short u16;
typedef short bf8v __attribute__((ext_vector_type(8)));
typedef float f4v __attribute__((ext_vector_type(4)));
typedef float f16v __attribute__((ext_vector_type(16)));

#define DEV static __device__ __forceinline__

constexpr int BB   = 64;
constexpr int NV   = 21;
constexpr int BN   = BB * NV;       // 1344
constexpr int PNUM = 255;
constexpr int D    = 128;
constexpr int PRED = 96;
constexpr int ROWS = BN * PNUM;     // 342720 = 64 * 5355
constexpr int KH   = D * PNUM;      // 32640 head K
constexpr int CH   = 30;            // head K chunks
constexpr int KPC  = KH / CH;       // 1088 = 34*32
constexpr int HITER = KPC / 32;     // 34
constexpr float EMA_SCALE = 0.70710678118654752440f;  // 1/sqrt(2)

DEV float bf2f(u16 h) { return __uint_as_float(((unsigned)h) << 16); }
DEV u16 f2bf(float f) {  // RNE (weight prepass only)
  unsigned u = __float_as_uint(f);
  return (u16)((u + 0x7fffu + ((u >> 16) & 1u)) >> 16);
}
// pack two floats to bf16 pair (round-half-up): lo = a, hi = b
DEV unsigned pkbf2(float a, float b) {
  unsigned ua = __float_as_uint(a) + 0x8000u;
  unsigned ub = __float_as_uint(b) + 0x8000u;
  return __builtin_amdgcn_perm(ub, ua, 0x07060302u);
}
DEV bf8v mk4(unsigned a, unsigned b, unsigned c, unsigned d) {
  int4 t = {(int)a, (int)b, (int)c, (int)d};
  bf8v r;
  __builtin_memcpy(&r, &t, 16);
  return r;
}
DEV bf8v ld8(const u16* p) {
  bf8v r;
  __builtin_memcpy(&r, p, 16);
  return r;
}
DEV f4v mfma16(bf8v a, bf8v b, f4v c) {
  return __builtin_amdgcn_mfma_f32_16x16x32_bf16(a, b, c, 0, 0, 0);
}
DEV f16v mfma32(bf8v a, bf8v b, f16v c) {
  return __builtin_amdgcn_mfma_f32_32x32x16_bf16(a, b, c, 0, 0, 0);
}
DEV f16v zero16() {
  f16v r;
#pragma unroll
  for (int i = 0; i < 16; i++) r[i] = 0.f;
  return r;
}

// B-fragment assembly via v_permlane32_swap_b32 (gfx950).
// Register layout: pk pair (x*, y*) holds output channels
//   c = base + {0..7} packed as x0={c0,c1}, x1={c2,c3}, y0={c4,c5}, y1={c6,c7}
//   with the two lane-halves (hh) holding interleaved 4-chan quads.
// v_permlane32_swap_b32 X, Y:  X' = {X.row0, Y.row0}, Y' = {X.row1, Y.row1}
// (rows = lane<32 / lane>=32 halves). Applied to the packed pair this yields
// the 32x32x16 B-operand fragment (lane l holds chans 16*ks+8*hh+{0..7} of its
// act-row) in 2 full-rate VALU ops. Verified correct in the r1 harness run.
DEV bf8v frag_pl(unsigned x0, unsigned y0, unsigned x1, unsigned y1) {
  asm("v_permlane32_swap_b32 %0, %1" : "+v"(x0), "+v"(y0));
  asm("v_permlane32_swap_b32 %0, %1" : "+v"(x1), "+v"(y1));
  return mk4(x0, x1, y0, y1);
}

// cross-half (xor 32) float add via permlane32_swap: a'={v.r0,v.r0},
// b'={v.r1,v.r1}; a'+b' = full reduce across the 32-lane halves.
DEV float xadd32(float v) {
  unsigned a = __float_as_uint(v), b = a;
  asm("v_permlane32_swap_b32 %0, %1" : "+v"(a), "+v"(b));
  return __uint_as_float(a) + __uint_as_float(b);
}

// ---------------- fused weight swizzle prepass (fp32 -> bf16 fragments) ----------------
// frag[((k>>3)*N + n)*8 + (k&7)] = src[k*N + n]; k >= K zero-filled.
__global__ void swz_all(
    const float* __restrict__ fw1, const float* __restrict__ fw2,
    const float* __restrict__ fwr, const float* __restrict__ ew1,
    const float* __restrict__ ew2, const float* __restrict__ ewr,
    const float* __restrict__ hw, u16* __restrict__ wb, u16* __restrict__ wsh) {
  int b = blockIdx.x;
  if (b >= 560) {  // head_w [d*255+l][96] -> fragments in k-order kp = l*128 + d
    int i = (b - 560) * 256 + threadIdx.x;
    if (i >= KH * PRED) return;
    int kp = i / PRED, n = i - kp * PRED;
    int l = kp >> 7, d = kp & 127;
    wsh[((size_t)(kp >> 3) * PRED + n) * 8 + (kp & 7)] =
        f2bf(hw[(size_t)(d * PNUM + l) * PRED + n]);
    return;
  }
  const float* src; u16* dst; int K, N, Kp;
  if (b < 32)       { src = fw1; dst = wb;          K = 16;  N = 256; Kp = 32; }
  else if (b < 160) { b -= 32;  src = fw2; dst = wb + 8192;  K = 256; N = 128; Kp = 256; }
  else if (b < 176) { b -= 160; src = fwr; dst = wb + 40960; K = 16;  N = 128; Kp = 32; }
  else {
    int e = (b - 176) >> 6; b = (b - 176) & 63;
    int l = e / 3, w = e - 3 * l;
    const float* basep = (w == 0) ? ew1 : (w == 1) ? ew2 : ewr;
    src = basep + (size_t)l * 16384;
    dst = wb + 45056 + e * 16384;
    K = 128; N = 128; Kp = 128;
  }
  int i = b * 256 + threadIdx.x;
  if (i >= Kp * N) return;
  int k = i / N, n = i - k * N;
  u16 v = (k < K) ? f2bf(src[(size_t)k * N + n]) : (u16)0;
  dst[((size_t)(k >> 3) * N + n) * 8 + (k & 7)] = v;
}

// ---------------- K1: fused gather + fp LEMblock + 2 encoder LEMblocks ----------------
// 32x32x16 MFMA, transposed (A=weight, B=act). Each wave owns 32 rows; lane's
// act-row = lane&31. Producer/consumer GROUP FUSION: h-group g (one mfma
// output, 32 chans) feeds exactly W2 K-slices 2g/2g+1, so h is never fully
// materialized (8 regs instead of 64/32). zpk is converted ONCE per layer to
// read-only fragments zfr[8] (destructive permlane, no defensive copies).
// Register budget ~165 combined -> 3 waves/SIMD (was 2).
__global__ __launch_bounds__(128, 3) void k_lem(
    const float* __restrict__ x,
    const u16* __restrict__ ws1, const float* __restrict__ b1,
    const u16* __restrict__ ws2, const u16* __restrict__ wsr,
    const float* __restrict__ b2, const float* __restrict__ br,
    const float* __restrict__ g, const float* __restrict__ be,
    const u16* __restrict__ wse, const float* __restrict__ eb1,
    const float* __restrict__ eb2, const float* __restrict__ ebr,
    const float* __restrict__ eg, const float* __restrict__ ebe,
    u16* __restrict__ zout) {
  __shared__ __align__(16) u16 zst[64 * 132];
  const int t = threadIdx.x;
  const int lane = t & 63, w = t >> 6;  // w: wave 0..1
  const int hh = lane >> 5, r5 = lane & 31;
  const int tile = blockIdx.x;
  const int row = tile * 64 + w * 32 + r5;

  // gather z0: lane holds patch elems [8*hh .. 8*hh+7] of its row (B-frag K=16)
  bf8v azv;
  {
    unsigned R = (unsigned)row;
    unsigned bn = R / 255u;
    unsigned p = R - bn * 255u;
    const float* px = x + (size_t)bn * 2048u + p * 8u + hh * 8;
    float4 v0 = *(const float4*)px;
    float4 v1 = *(const float4*)(px + 4);
    azv = mk4(pkbf2(v0.x, v0.y), pkbf2(v0.z, v0.w),
              pkbf2(v1.x, v1.y), pkbf2(v1.z, v1.w));
  }

  f16v acc[4];        // GEMM-B accumulator (64 chans/lane)
  unsigned zpk[4][4][2];  // packed z (128 chans), rebuilt per LN
  bf8v zfr[8];        // z as B-fragments (K-slices), rebuilt per layer

  // ================= fp block: z1 = LN(W2^T relu(W1^T z0 + b1) + Wr^T z0 + b) ====
  {
    // Wr init: acc = Wr^T z0
#pragma unroll
    for (int gg = 0; gg < 4; gg++)
      acc[gg] = mfma32(ld8(wsr + ((size_t)(hh * 128 + gg * 32 + r5)) * 8), azv,
                       zero16());
    // fused h-groups: produce h_g (32 chans), consume into W2 slices 2g,2g+1
#pragma unroll
    for (int gq = 0; gq < 8; gq++) {
      bf8v w2x[4], w2y[4];
#pragma unroll
      for (int gg = 0; gg < 4; gg++)
        w2x[gg] = ld8(ws2 + ((size_t)((4 * gq + hh) * 128 + gg * 32 + r5)) * 8);
#pragma unroll
      for (int gg = 0; gg < 4; gg++)
        w2y[gg] = ld8(ws2 + ((size_t)((4 * gq + 2 + hh) * 128 + gg * 32 + r5)) * 8);
      bf8v w1f = ld8(ws1 + ((size_t)(hh * 256 + gq * 32 + r5)) * 8);
      f16v hv = mfma32(w1f, azv, zero16());
      unsigned hq[4][2];
#pragma unroll
      for (int wq = 0; wq < 4; wq++) {
        int c0 = gq * 32 + wq * 8 + 4 * hh;
        float4 bv = *(const float4*)(b1 + c0);
        float v0 = fmaxf(hv[wq * 4 + 0] + bv.x, 0.f);
        float v1 = fmaxf(hv[wq * 4 + 1] + bv.y, 0.f);
        float v2 = fmaxf(hv[wq * 4 + 2] + bv.z, 0.f);
        float v3 = fmaxf(hv[wq * 4 + 3] + bv.w, 0.f);
        hq[wq][0] = pkbf2(v0, v1);
        hq[wq][1] = pkbf2(v2, v3);
      }
      bf8v f0 = frag_pl(hq[0][0], hq[1][0], hq[0][1], hq[1][1]);
      bf8v f1 = frag_pl(hq[2][0], hq[3][0], hq[2][1], hq[3][1]);
#pragma unroll
      for (int gg = 0; gg < 4; gg++) acc[gg] = mfma32(w2x[gg], f0, acc[gg]);
#pragma unroll
      for (int gg = 0; gg < 4; gg++) acc[gg] = mfma32(w2y[gg], f1, acc[gg]);
    }
    // bias + LN -> zpk  (4-way partial sums for short dep chains)
    float sa[4], qa[4];
#pragma unroll
    for (int gg = 0; gg < 4; gg++) {
      float s = 0.f, q = 0.f;
#pragma unroll
      for (int wq4 = 0; wq4 < 4; wq4++) {
        int c0 = gg * 32 + wq4 * 8 + 4 * hh;
        float4 bv2 = *(const float4*)(b2 + c0);
        float4 bvr = *(const float4*)(br + c0);
        acc[gg][wq4 * 4 + 0] += bv2.x + bvr.x;
        acc[gg][wq4 * 4 + 1] += bv2.y + bvr.y;
        acc[gg][wq4 * 4 + 2] += bv2.z + bvr.z;
        acc[gg][wq4 * 4 + 3] += bv2.w + bvr.w;
#pragma unroll
        for (int sidx = 0; sidx < 4; sidx++) {
          float v = acc[gg][wq4 * 4 + sidx];
          s += v; q += v * v;
        }
      }
      sa[gg] = s; qa[gg] = q;
    }
    float s = xadd32((sa[0] + sa[1]) + (sa[2] + sa[3]));
    float q = xadd32((qa[0] + qa[1]) + (qa[2] + qa[3]));
    float mean = s * (1.f / 128.f);
    float rstd = rsqrtf(q * (1.f / 128.f) - mean * mean + 1e-5f);
#pragma unroll
    for (int gg = 0; gg < 4; gg++)
#pragma unroll
      for (int wq4 = 0; wq4 < 4; wq4++) {
        int c0 = gg * 32 + wq4 * 8 + 4 * hh;
        float4 gv = *(const float4*)(g + c0);
        float4 bv = *(const float4*)(be + c0);
        float v0 = (acc[gg][wq4 * 4 + 0] - mean) * rstd * gv.x + bv.x;
        float v1 = (acc[gg][wq4 * 4 + 1] - mean) * rstd * gv.y + bv.y;
        float v2 = (acc[gg][wq4 * 4 + 2] - mean) * rstd * gv.z + bv.z;
        float v3 = (acc[gg][wq4 * 4 + 3] - mean) * rstd * gv.w + bv.w;
        zpk[gg][wq4][0] = pkbf2(v0, v1);
        zpk[gg][wq4][1] = pkbf2(v2, v3);
      }
  }

  // ================= encoder layers =================
#pragma unroll 1
  for (int L = 0; L < 2; L++) {
    const u16* w1p = wse + (size_t)(L * 3 + 0) * 16384;
    const u16* w2p = wse + (size_t)(L * 3 + 1) * 16384;
    const u16* wrp = wse + (size_t)(L * 3 + 2) * 16384;
    // zpk -> zfr fragments (destructive; zpk dead until next LN)
#pragma unroll
    for (int gq = 0; gq < 4; gq++) {
      zfr[2 * gq] =
          frag_pl(zpk[gq][0][0], zpk[gq][1][0], zpk[gq][0][1], zpk[gq][1][1]);
      zfr[2 * gq + 1] =
          frag_pl(zpk[gq][2][0], zpk[gq][3][0], zpk[gq][2][1], zpk[gq][3][1]);
    }
    // Wr pass: acc = Wr^T z  (4 independent 8-deep mfma chains)
#pragma unroll
    for (int gg = 0; gg < 4; gg++) acc[gg] = zero16();
#pragma unroll
    for (int ks = 0; ks < 8; ks++)
#pragma unroll
      for (int gg = 0; gg < 4; gg++) {
        bf8v wf = ld8(wrp + ((size_t)((2 * ks + hh) * 128 + gg * 32 + r5)) * 8);
        acc[gg] = mfma32(wf, zfr[ks], acc[gg]);
      }
    // fused W1/W2 groups: h2_g = relu(W1_g^T z + eb1); acc += W2 slices 2g,2g+1
#pragma unroll
    for (int gq = 0; gq < 4; gq++) {
      bf8v w2x[4], w2y[4];
#pragma unroll
      for (int gg = 0; gg < 4; gg++)
        w2x[gg] = ld8(w2p + ((size_t)((4 * gq + hh) * 128 + gg * 32 + r5)) * 8);
#pragma unroll
      for (int gg = 0; gg < 4; gg++)
        w2y[gg] = ld8(w2p + ((size_t)((4 * gq + 2 + hh) * 128 + gg * 32 + r5)) * 8);
      f16v av = zero16();
#pragma unroll
      for (int ks = 0; ks < 8; ks++) {
        bf8v wf = ld8(w1p + ((size_t)((2 * ks + hh) * 128 + gq * 32 + r5)) * 8);
        av = mfma32(wf, zfr[ks], av);
      }
      unsigned hq[4][2];
#pragma unroll
      for (int wq = 0; wq < 4; wq++) {
        int c0 = gq * 32 + wq * 8 + 4 * hh;
        float4 bv = *(const float4*)(eb1 + L * 128 + c0);
        float v0 = fmaxf(av[wq * 4 + 0] + bv.x, 0.f);
        float v1 = fmaxf(av[wq * 4 + 1] + bv.y, 0.f);
        float v2 = fmaxf(av[wq * 4 + 2] + bv.z, 0.f);
        float v3 = fmaxf(av[wq * 4 + 3] + bv.w, 0.f);
        hq[wq][0] = pkbf2(v0, v1);
        hq[wq][1] = pkbf2(v2, v3);
      }
      bf8v f0 = frag_pl(hq[0][0], hq[1][0], hq[0][1], hq[1][1]);
      bf8v f1 = frag_pl(hq[2][0], hq[3][0], hq[2][1], hq[3][1]);
#pragma unroll
      for (int gg = 0; gg < 4; gg++) acc[gg] = mfma32(w2x[gg], f0, acc[gg]);
#pragma unroll
      for (int gg = 0; gg < 4; gg++) acc[gg] = mfma32(w2y[gg], f1, acc[gg]);
    }
    // bias + LN
    float sa[4], qa[4];
#pragma unroll
    for (int gg = 0; gg < 4; gg++) {
      float s = 0.f, q = 0.f;
#pragma unroll
      for (int wq4 = 0; wq4 < 4; wq4++) {
        int c0 = gg * 32 + wq4 * 8 + 4 * hh;
        float4 bv2 = *(const float4*)(eb2 + L * 128 + c0);
        float4 bvr = *(const float4*)(ebr + L * 128 + c0);
        acc[gg][wq4 * 4 + 0] += bv2.x + bvr.x;
        acc[gg][wq4 * 4 + 1] += bv2.y + bvr.y;
        acc[gg][wq4 * 4 + 2] += bv2.z + bvr.z;
        acc[gg][wq4 * 4 + 3] += bv2.w + bvr.w;
#pragma unroll
        for (int sidx = 0; sidx < 4; sidx++) {
          float v = acc[gg][wq4 * 4 + sidx];
          s += v; q += v * v;
        }
      }
      sa[gg] = s; qa[gg] = q;
    }
    float s = xadd32((sa[0] + sa[1]) + (sa[2] + sa[3]));
    float q = xadd32((qa[0] + qa[1]) + (qa[2] + qa[3]));
    float mean = s * (1.f / 128.f);
    float rstd = rsqrtf(q * (1.f / 128.f) - mean * mean + 1e-5f);
#pragma unroll
    for (int gg = 0; gg < 4; gg++)
#pragma unroll
      for (int wq4 = 0; wq4 < 4; wq4++) {
        int c0 = gg * 32 + wq4 * 8 + 4 * hh;
        float4 gv = *(const float4*)(eg + L * 128 + c0);
        float4 bv = *(const float4*)(ebe + L * 128 + c0);
        float v0 = (acc[gg][wq4 * 4 + 0] - mean) * rstd * gv.x + bv.x;
        float v1 = (acc[gg][wq4 * 4 + 1] - mean) * rstd * gv.y + bv.y;
        float v2 = (acc[gg][wq4 * 4 + 2] - mean) * rstd * gv.z + bv.z;
        float v3 = (acc[gg][wq4 * 4 + 3] - mean) * rstd * gv.w + bv.w;
        unsigned plo = pkbf2(v0, v1), phi = pkbf2(v2, v3);
        if (L == 0) {
          zpk[gg][wq4][0] = plo;
          zpk[gg][wq4][1] = phi;
        } else {
          uint2 pv = {plo, phi};
          *(uint2*)(zst + (w * 32 + r5) * 132 + c0) = pv;
        }
      }
  }

  // per-wave coalesced store of its own 32 rows (same-wave LDS RAW: no barrier)
#pragma unroll
  for (int it = 0; it < 8; it++) {
    int lu = it * 64 + lane;
    int rr = lu >> 4, seg = lu & 15;
    int orow = w * 32 + rr;
    *(uint4*)(zout + ((size_t)tile * 64 + orow) * 128 + seg * 8) =
        *(const uint4*)(zst + orow * 132 + seg * 8);
  }
}

// ---------------- K2: MultiHeadEMA (2-state scan) + residual + silu, IN-PLACE ----------------
__global__ __launch_bounds__(128) void k_ema(
    u16* __restrict__ z,
    const float* __restrict__ pdel, const float* __restrict__ palp,
    const float* __restrict__ pbet, const float* __restrict__ pgam,
    const float* __restrict__ pome) {
  __shared__ __align__(16) u16 zc[64 * 128];
  const int t = threadIdx.x;  // channel d
  const int bn = blockIdx.x;
  float p0 = 1.f / (1.f + __expf(-pdel[t * 2 + 0]));
  float p1 = 1.f / (1.f + __expf(-pdel[t * 2 + 1]));
  float q0 = 1.f - p0 / (1.f + __expf(-palp[t * 2 + 0]));
  float q1 = 1.f - p1 / (1.f + __expf(-palp[t * 2 + 1]));
  float w0 = p0 * pbet[t * 2 + 0] * pgam[t * 2 + 0] * EMA_SCALE;
  float w1 = p1 * pbet[t * 2 + 1] * pgam[t * 2 + 1] * EMA_SCALE;
  float om = pome[t];
  float s0 = 0.f, s1 = 0.f;
  u16* slab = z + (size_t)bn * KH;

  for (int ch = 0; ch < 4; ch++) {
    int nrow = (ch < 3) ? 64 : 63;
    int nval = nrow * 128;
    for (int i = t * 8; i < nval; i += 128 * 8)
      *(uint4*)(zc + i) = *(const uint4*)(slab + ch * 8192 + i);
    __syncthreads();
    for (int j0 = 0; j0 < nrow; j0 += 8) {
      float xs[8];
#pragma unroll
      for (int jj = 0; jj < 8; jj++)
        if (j0 + jj < nrow) xs[jj] = bf2f(zc[(j0 + jj) * 128 + t]);
#pragma unroll
      for (int jj = 0; jj < 8; jj++)
        if (j0 + jj < nrow) {
          float xv = xs[jj];
          s0 = q0 * s0 + xv;
          s1 = q1 * s1 + xv;
          float v = w0 * s0 + w1 * s1 + om * xv;
          xs[jj] = v / (1.f + __expf(-v));  // silu
        }
#pragma unroll
      for (int jj = 0; jj < 8; jj++)
        if (j0 + jj < nrow)
          zc[(j0 + jj) * 128 + t] = (u16)((__float_as_uint(xs[jj]) + 0x8000u) >> 16);
    }
    __syncthreads();
    for (int i = t * 8; i < nval; i += 128 * 8)
      *(uint4*)(slab + ch * 8192 + i) = *(const uint4*)(zc + i);
    __syncthreads();
  }
}

// ---------------- K3: head GEMM partials (K split into 30 chunks of 1088) ----------------
__global__ __launch_bounds__(256) void k_head(
    const u16* __restrict__ u, const u16* __restrict__ whs, float* __restrict__ part) {
  const int t = threadIdx.x;
  const int lane = t & 63, wid = t >> 6;
  const int quad = lane >> 4, lc = lane & 15;
  const int tile = blockIdx.x;  // 0..20
  const int ch = blockIdx.y;    // 0..29
  const int m0 = tile * 64 + wid * 16;
  const u16* Ab = u + (size_t)(m0 + lc) * KH + (size_t)ch * KPC;
  const int g0 = ch * (KPC / 8);  // base k-group
  f4v acc[6];
#pragma unroll
  for (int n = 0; n < 6; n++) acc[n] = (f4v){0.f, 0.f, 0.f, 0.f};
  bf8v a_nxt = ld8(Ab + quad * 8);
  bf8v b_nxt[6];
#pragma unroll
  for (int n = 0; n < 6; n++)
    b_nxt[n] = ld8(whs + ((size_t)(g0 + quad) * PRED + n * 16 + lc) * 8);
  for (int ks = 0; ks < HITER; ks++) {
    bf8v a_cur = a_nxt;
    bf8v b_cur[6];
#pragma unroll
    for (int n = 0; n < 6; n++) b_cur[n] = b_nxt[n];
    if (ks < HITER - 1) {
      a_nxt = ld8(Ab + (ks + 1) * 32 + quad * 8);
#pragma unroll
      for (int n = 0; n < 6; n++)
        b_nxt[n] = ld8(whs + ((size_t)(g0 + (ks + 1) * 4 + quad) * PRED + n * 16 + lc) * 8);
    }
#pragma unroll
    for (int n = 0; n < 6; n++) acc[n] = mfma16(a_cur, b_cur[n], acc[n]);
  }
#pragma unroll
  for (int n = 0; n < 6; n++) {
    int col = n * 16 + lc;
#pragma unroll
    for (int r = 0; r < 4; r++)
      part[((size_t)ch * BN + m0 + quad * 4 + r) * PRED + col] = acc[n][r];
  }
}

// ---------------- K4: reduce partials + bias -> fp32 out ----------------
__global__ __launch_bounds__(256) void k_red(
    const float* __restrict__ part, const float* __restrict__ hb, float* __restrict__ out) {
  int i = blockIdx.x * 256 + threadIdx.x;
  if (i >= BN * PRED) return;
  int row = i / PRED, col = i - row * PRED;
  float s = hb[col];
#pragma unroll 5
  for (int c = 0; c < CH; c++) s += part[((size_t)c * BN + row) * PRED + col];
  out[i] = s;
}

// ---------------- host ----------------
extern "C" void kernel_launch(void* const* d_in, const int* in_sizes, int n_in,
                              void* d_out, int out_size, void* d_ws, size_t ws_size,
                              hipStream_t stream) {
  const float* x      = (const float*)d_in[0];
  const float* fp_w1  = (const float*)d_in[1];
  const float* fp_b1  = (const float*)d_in[2];
  const float* fp_w2  = (const float*)d_in[3];
  const float* fp_b2  = (const float*)d_in[4];
  const float* fp_wr  = (const float*)d_in[5];
  const float* fp_br  = (const float*)d_in[6];
  const float* fp_g   = (const float*)d_in[7];
  const float* fp_be  = (const float*)d_in[8];
  const float* enc_w1 = (const float*)d_in[9];
  const float* enc_b1 = (const float*)d_in[10];
  const float* enc_w2 = (const float*)d_in[11];
  const float* enc_b2 = (const float*)d_in[12];
  const float* enc_wr = (const float*)d_in[13];
  const float* enc_br = (const float*)d_in[14];
  const float* enc_g  = (const float*)d_in[15];
  const float* enc_be = (const float*)d_in[16];
  const float* e_del  = (const float*)d_in[17];
  const float* e_alp  = (const float*)d_in[18];
  const float* e_bet  = (const float*)d_in[19];
  const float* e_gam  = (const float*)d_in[20];
  const float* e_om   = (const float*)d_in[21];
  const float* head_w = (const float*)d_in[22];
  const float* head_b = (const float*)d_in[23];

  // ws layout (bytes):
  //   [0, 87736320)             z3 / u  (bf16, [ROWS][128])
  //   [87736320, 103219200)     part    (fp32, [30][1344][96])
  //   [103219200, ...)          swizzled bf16 weights (~6.6 MB)
  char* base = (char*)d_ws;
  u16* z3 = (u16*)base;
  const size_t EZB = (size_t)ROWS * 128 * 2;        // 87,736,320
  float* part = (float*)(base + EZB);
  const size_t PARTB = (size_t)CH * BN * PRED * 4;  // 15,482,880
  u16* wb = (u16*)(base + EZB + PARTB);
  // wb offsets (u16): ws1=0(8192), ws2=8192(32768), wsr=40960(4096),
  //                   wse=45056(6*16384), wsh=143360(32640*96)
  u16* ws1 = wb;
  u16* ws2 = wb + 8192;
  u16* wsr = wb + 40960;
  u16* wse = wb + 45056;
  u16* wsh = wb + 143360;

  swz_all<<<560 + (KH * PRED + 255) / 256, 256, 0, stream>>>(
      fp_w1, fp_w2, fp_wr, enc_w1, enc_w2, enc_wr, head_w, wb, wsh);

  k_lem<<<ROWS / 64, 128, 0, stream>>>(x, ws1, fp_b1, ws2, wsr, fp_b2, fp_br, fp_g, fp_be,
                                       wse, enc_b1, enc_b2, enc_br, enc_g, enc_be, z3);
  k_ema<<<BN, 128, 0, stream>>>(z3, e_del, e_alp, e_bet, e_gam, e_om);
  k_head<<<dim3(21, CH), 256, 0, stream>>>(z3, wsh, part);
  k_red<<<(BN * PRED + 255) / 256, 256, 0, stream>>>(part, head_b, (float*)d_out);
}

// Round 4
// 462.608 us; speedup vs baseline: 1.1420x; 1.1420x over previous
//
#include <hip/hip_runtime.h>

typedef unsigned short u16;
typedef short bf8v __attribute__((ext_vector_type(8)));
typedef float f4v __attribute__((ext_vector_type(4)));
typedef float f16v __attribute__((ext_vector_type(16)));

#define DEV static __device__ __forceinline__

constexpr int BB   = 64;
constexpr int NV   = 21;
constexpr int BN   = BB * NV;       // 1344
constexpr int PNUM = 255;
constexpr int D    = 128;
constexpr int PRED = 96;
constexpr int ROWS = BN * PNUM;     // 342720 = 64 * 5355
constexpr int KH   = D * PNUM;      // 32640 head K
constexpr int CH   = 30;            // head K chunks
constexpr int KPC  = KH / CH;       // 1088 = 34*32
constexpr int HITER = KPC / 32;     // 34
constexpr float EMA_SCALE = 0.70710678118654752440f;  // 1/sqrt(2)

DEV float bf2f(u16 h) { return __uint_as_float(((unsigned)h) << 16); }
DEV u16 f2bf(float f) {  // RNE (weight prepass only)
  unsigned u = __float_as_uint(f);
  return (u16)((u + 0x7fffu + ((u >> 16) & 1u)) >> 16);
}
// pack two floats to bf16 pair (round-half-up): lo = a, hi = b
DEV unsigned pkbf2(float a, float b) {
  unsigned ua = __float_as_uint(a) + 0x8000u;
  unsigned ub = __float_as_uint(b) + 0x8000u;
  return __builtin_amdgcn_perm(ub, ua, 0x07060302u);
}
DEV bf8v mk4(unsigned a, unsigned b, unsigned c, unsigned d) {
  int4 t = {(int)a, (int)b, (int)c, (int)d};
  bf8v r;
  __builtin_memcpy(&r, &t, 16);
  return r;
}
DEV bf8v ld8(const u16* p) {
  bf8v r;
  __builtin_memcpy(&r, p, 16);
  return r;
}
DEV f4v mfma16(bf8v a, bf8v b, f4v c) {
  return __builtin_amdgcn_mfma_f32_16x16x32_bf16(a, b, c, 0, 0, 0);
}
DEV f16v mfma32(bf8v a, bf8v b, f16v c) {
  return __builtin_amdgcn_mfma_f32_32x32x16_bf16(a, b, c, 0, 0, 0);
}
DEV f16v zero16() {
  f16v r;
#pragma unroll
  for (int i = 0; i < 16; i++) r[i] = 0.f;
  return r;
}

// Assemble B-operand fragment (8 contiguous channels [16*ks+8*hh .. +7] of this
// lane's row) from packed D-layout register array pk[g][w][2] via one
// shfl_xor(32) pair exchange. Loops calling this are fully unrolled, so the
// indices are compile-time constants post-unroll (SROA keeps pk in registers).
// (R0-proven path; permlane variant abandoned: VALU-write->MFMA-read hazard
// with inline asm caused timing-dependent corruption in r3.)
#define FRAG_ASM(pk, ks, hh)                                                   \
  ({                                                                           \
    int _g = (ks) >> 1, _lw = 2 * ((ks) & 1);                                  \
    unsigned _A0 = pk[_g][_lw][0], _A1 = pk[_g][_lw][1];                       \
    unsigned _B0 = pk[_g][_lw + 1][0], _B1 = pk[_g][_lw + 1][1];               \
    unsigned _own0 = (hh) ? _B0 : _A0, _own1 = (hh) ? _B1 : _A1;               \
    unsigned _snd0 = (hh) ? _A0 : _B0, _snd1 = (hh) ? _A1 : _B1;               \
    unsigned _o0 = (unsigned)__shfl_xor((int)_snd0, 32, 64);                   \
    unsigned _o1 = (unsigned)__shfl_xor((int)_snd1, 32, 64);                   \
    mk4((hh) ? _o0 : _own0, (hh) ? _o1 : _own1,                                \
        (hh) ? _own0 : _o0, (hh) ? _own1 : _o1);                               \
  })

// ---------------- fused weight swizzle prepass (fp32 -> bf16 fragments) ----------------
// frag[((k>>3)*N + n)*8 + (k&7)] = src[k*N + n]; k >= K zero-filled.
__global__ void swz_all(
    const float* __restrict__ fw1, const float* __restrict__ fw2,
    const float* __restrict__ fwr, const float* __restrict__ ew1,
    const float* __restrict__ ew2, const float* __restrict__ ewr,
    const float* __restrict__ hw, u16* __restrict__ wb, u16* __restrict__ wsh) {
  int b = blockIdx.x;
  if (b >= 560) {  // head_w [d*255+l][96] -> fragments in k-order kp = l*128 + d
    int i = (b - 560) * 256 + threadIdx.x;
    if (i >= KH * PRED) return;
    int kp = i / PRED, n = i - kp * PRED;
    int l = kp >> 7, d = kp & 127;
    wsh[((size_t)(kp >> 3) * PRED + n) * 8 + (kp & 7)] =
        f2bf(hw[(size_t)(d * PNUM + l) * PRED + n]);
    return;
  }
  const float* src; u16* dst; int K, N, Kp;
  if (b < 32)       { src = fw1; dst = wb;          K = 16;  N = 256; Kp = 32; }
  else if (b < 160) { b -= 32;  src = fw2; dst = wb + 8192;  K = 256; N = 128; Kp = 256; }
  else if (b < 176) { b -= 160; src = fwr; dst = wb + 40960; K = 16;  N = 128; Kp = 32; }
  else {
    int e = (b - 176) >> 6; b = (b - 176) & 63;
    int l = e / 3, w = e - 3 * l;
    const float* basep = (w == 0) ? ew1 : (w == 1) ? ew2 : ewr;
    src = basep + (size_t)l * 16384;
    dst = wb + 45056 + e * 16384;
    K = 128; N = 128; Kp = 128;
  }
  int i = b * 256 + threadIdx.x;
  if (i >= Kp * N) return;
  int k = i / N, n = i - k * N;
  u16 v = (k < K) ? f2bf(src[(size_t)k * N + n]) : (u16)0;
  dst[((size_t)(k >> 3) * N + n) * 8 + (k & 7)] = v;
}

// ---------------- K1: fused gather + fp LEMblock + 2 encoder LEMblocks ----------------
// 32x32x16 MFMA, transposed (A=weight, B=act). Each wave owns 32 rows; lane's
// act-row = lane&31. Between-GEMM relayout done IN REGISTERS via shfl_xor(32)
// (no act LDS, no barriers). LDS only stages the final 64x128 output tile.
// R4 delta vs R0 (proven 200us): weight prefetch depth 1 -> 2 (wq[3] rotation)
// in the pipelined K-loops, so loads issue ~256cy (2 iters) before use and
// cover the ~200-225cy L2-hit latency.  Everything else identical to R0.
__global__ __launch_bounds__(128, 2) void k_lem(
    const float* __restrict__ x,
    const u16* __restrict__ ws1, const float* __restrict__ b1,
    const u16* __restrict__ ws2, const u16* __restrict__ wsr,
    const float* __restrict__ b2, const float* __restrict__ br,
    const float* __restrict__ g, const float* __restrict__ be,
    const u16* __restrict__ wse, const float* __restrict__ eb1,
    const float* __restrict__ eb2, const float* __restrict__ ebr,
    const float* __restrict__ eg, const float* __restrict__ ebe,
    u16* __restrict__ zout) {
  __shared__ __align__(16) u16 zst[64 * 132];
  const int t = threadIdx.x;
  const int lane = t & 63, w = t >> 6;  // w: wave 0..1
  const int hh = lane >> 5, r5 = lane & 31;
  const int tile = blockIdx.x;
  const int row = tile * 64 + w * 32 + r5;

  // gather z0: lane holds patch elems [8*hh .. 8*hh+7] of its row (B-frag K=16)
  bf8v azv;
  {
    unsigned R = (unsigned)row;
    unsigned bn = R / 255u;
    unsigned p = R - bn * 255u;
    const float* px = x + (size_t)bn * 2048u + p * 8u + hh * 8;
    float4 v0 = *(const float4*)px;
    float4 v1 = *(const float4*)(px + 4);
    azv = mk4(pkbf2(v0.x, v0.y), pkbf2(v0.z, v0.w),
              pkbf2(v1.x, v1.y), pkbf2(v1.z, v1.w));
  }

  unsigned hpk[8][4][2];  // packed h (256 chans, D-layout halves)
  unsigned zpk[4][4][2];  // packed z (128 chans)

  // ---- GEMM1: h = relu(W1^T z0 + b1), two halves of 128 cols ----
#pragma unroll
  for (int half = 0; half < 2; half++) {
    f16v a[4];
#pragma unroll
    for (int gg = 0; gg < 4; gg++) {
      bf8v wf = ld8(ws1 + ((size_t)(hh * 256 + (half * 4 + gg) * 32 + r5)) * 8);
      a[gg] = mfma32(wf, azv, zero16());
    }
#pragma unroll
    for (int gg = 0; gg < 4; gg++)
#pragma unroll
      for (int wq = 0; wq < 4; wq++) {
        int c0 = (half * 4 + gg) * 32 + wq * 8 + 4 * hh;
        float4 bv = *(const float4*)(b1 + c0);
        float v0 = fmaxf(a[gg][wq * 4 + 0] + bv.x, 0.f);
        float v1 = fmaxf(a[gg][wq * 4 + 1] + bv.y, 0.f);
        float v2 = fmaxf(a[gg][wq * 4 + 2] + bv.z, 0.f);
        float v3 = fmaxf(a[gg][wq * 4 + 3] + bv.w, 0.f);
        hpk[half * 4 + gg][wq][0] = pkbf2(v0, v1);
        hpk[half * 4 + gg][wq][1] = pkbf2(v2, v3);
      }
  }

  // ---- GEMM2: y1 = W2^T h + Wr^T z0 + b2 + br -> LN -> z1 ----
  {
    f16v acc[4];
#pragma unroll
    for (int gg = 0; gg < 4; gg++) {
      bf8v wf = ld8(wsr + ((size_t)(hh * 128 + gg * 32 + r5)) * 8);
      acc[gg] = mfma32(wf, azv, zero16());
    }
    bf8v wq[3][4];
#pragma unroll
    for (int gg = 0; gg < 4; gg++)
      wq[0][gg] = ld8(ws2 + ((size_t)(hh * 128 + gg * 32 + r5)) * 8);
#pragma unroll
    for (int gg = 0; gg < 4; gg++)
      wq[1][gg] = ld8(ws2 + ((size_t)((2 + hh) * 128 + gg * 32 + r5)) * 8);
    bf8v bf_cur = FRAG_ASM(hpk, 0, hh);
#pragma unroll
    for (int ks = 0; ks < 16; ks++) {
      if (ks + 2 < 16) {
#pragma unroll
        for (int gg = 0; gg < 4; gg++)
          wq[(ks + 2) % 3][gg] =
              ld8(ws2 + ((size_t)((2 * (ks + 2) + hh) * 128 + gg * 32 + r5)) * 8);
      }
      bf8v bf_nxt = bf_cur;
      if (ks + 1 < 16) bf_nxt = FRAG_ASM(hpk, ks + 1, hh);
#pragma unroll
      for (int gg = 0; gg < 4; gg++) acc[gg] = mfma32(wq[ks % 3][gg], bf_cur, acc[gg]);
      bf_cur = bf_nxt;
    }
    // bias + LN
    float s = 0.f, s2 = 0.f;
#pragma unroll
    for (int gg = 0; gg < 4; gg++)
#pragma unroll
      for (int wq4 = 0; wq4 < 4; wq4++) {
        int c0 = gg * 32 + wq4 * 8 + 4 * hh;
        float4 bv2 = *(const float4*)(b2 + c0);
        float4 bvr = *(const float4*)(br + c0);
        acc[gg][wq4 * 4 + 0] += bv2.x + bvr.x;
        acc[gg][wq4 * 4 + 1] += bv2.y + bvr.y;
        acc[gg][wq4 * 4 + 2] += bv2.z + bvr.z;
        acc[gg][wq4 * 4 + 3] += bv2.w + bvr.w;
#pragma unroll
        for (int sidx = 0; sidx < 4; sidx++) {
          float v = acc[gg][wq4 * 4 + sidx];
          s += v; s2 += v * v;
        }
      }
    s += __shfl_xor(s, 32, 64); s2 += __shfl_xor(s2, 32, 64);
    float mean = s * (1.f / 128.f);
    float rstd = rsqrtf(s2 * (1.f / 128.f) - mean * mean + 1e-5f);
#pragma unroll
    for (int gg = 0; gg < 4; gg++)
#pragma unroll
      for (int wq4 = 0; wq4 < 4; wq4++) {
        int c0 = gg * 32 + wq4 * 8 + 4 * hh;
        float4 gv = *(const float4*)(g + c0);
        float4 bv = *(const float4*)(be + c0);
        float v0 = (acc[gg][wq4 * 4 + 0] - mean) * rstd * gv.x + bv.x;
        float v1 = (acc[gg][wq4 * 4 + 1] - mean) * rstd * gv.y + bv.y;
        float v2 = (acc[gg][wq4 * 4 + 2] - mean) * rstd * gv.z + bv.z;
        float v3 = (acc[gg][wq4 * 4 + 3] - mean) * rstd * gv.w + bv.w;
        zpk[gg][wq4][0] = pkbf2(v0, v1);
        zpk[gg][wq4][1] = pkbf2(v2, v3);
      }
  }

  // ---- encoder layers ----
#pragma unroll 1
  for (int L = 0; L < 2; L++) {
    const u16* w1p = wse + (size_t)(L * 3 + 0) * 16384;
    const u16* w2p = wse + (size_t)(L * 3 + 1) * 16384;
    const u16* wrp = wse + (size_t)(L * 3 + 2) * 16384;
    unsigned hp2[4][4][2];
    // GEMM-A: h2 = relu(W1^T z + eb1)
    {
      f16v a2[4];
#pragma unroll
      for (int gg = 0; gg < 4; gg++) a2[gg] = zero16();
      bf8v wq[3][4];
#pragma unroll
      for (int gg = 0; gg < 4; gg++)
        wq[0][gg] = ld8(w1p + ((size_t)(hh * 128 + gg * 32 + r5)) * 8);
#pragma unroll
      for (int gg = 0; gg < 4; gg++)
        wq[1][gg] = ld8(w1p + ((size_t)((2 + hh) * 128 + gg * 32 + r5)) * 8);
      bf8v bf_cur = FRAG_ASM(zpk, 0, hh);
#pragma unroll
      for (int ks = 0; ks < 8; ks++) {
        if (ks + 2 < 8) {
#pragma unroll
          for (int gg = 0; gg < 4; gg++)
            wq[(ks + 2) % 3][gg] =
                ld8(w1p + ((size_t)((2 * (ks + 2) + hh) * 128 + gg * 32 + r5)) * 8);
        }
        bf8v bf_nxt = bf_cur;
        if (ks + 1 < 8) bf_nxt = FRAG_ASM(zpk, ks + 1, hh);
#pragma unroll
        for (int gg = 0; gg < 4; gg++) a2[gg] = mfma32(wq[ks % 3][gg], bf_cur, a2[gg]);
        bf_cur = bf_nxt;
      }
#pragma unroll
      for (int gg = 0; gg < 4; gg++)
#pragma unroll
        for (int wq4 = 0; wq4 < 4; wq4++) {
          int c0 = gg * 32 + wq4 * 8 + 4 * hh;
          float4 bv = *(const float4*)(eb1 + L * 128 + c0);
          float v0 = fmaxf(a2[gg][wq4 * 4 + 0] + bv.x, 0.f);
          float v1 = fmaxf(a2[gg][wq4 * 4 + 1] + bv.y, 0.f);
          float v2 = fmaxf(a2[gg][wq4 * 4 + 2] + bv.z, 0.f);
          float v3 = fmaxf(a2[gg][wq4 * 4 + 3] + bv.w, 0.f);
          hp2[gg][wq4][0] = pkbf2(v0, v1);
          hp2[gg][wq4][1] = pkbf2(v2, v3);
        }
    }
    // GEMM-B: y = W2^T h2 + Wr^T z + biases -> LN
    f16v acc[4];
#pragma unroll
    for (int gg = 0; gg < 4; gg++) acc[gg] = zero16();
    {
      bf8v wq[3][4];
#pragma unroll
      for (int gg = 0; gg < 4; gg++)
        wq[0][gg] = ld8(w2p + ((size_t)(hh * 128 + gg * 32 + r5)) * 8);
#pragma unroll
      for (int gg = 0; gg < 4; gg++)
        wq[1][gg] = ld8(w2p + ((size_t)((2 + hh) * 128 + gg * 32 + r5)) * 8);
      bf8v bf_cur = FRAG_ASM(hp2, 0, hh);
#pragma unroll
      for (int ks = 0; ks < 8; ks++) {
        if (ks + 2 < 8) {
#pragma unroll
          for (int gg = 0; gg < 4; gg++)
            wq[(ks + 2) % 3][gg] =
                ld8(w2p + ((size_t)((2 * (ks + 2) + hh) * 128 + gg * 32 + r5)) * 8);
        }
        bf8v bf_nxt = bf_cur;
        if (ks + 1 < 8) bf_nxt = FRAG_ASM(hp2, ks + 1, hh);
#pragma unroll
        for (int gg = 0; gg < 4; gg++) acc[gg] = mfma32(wq[ks % 3][gg], bf_cur, acc[gg]);
        bf_cur = bf_nxt;
      }
#pragma unroll
      for (int gg = 0; gg < 4; gg++)
        wq[0][gg] = ld8(wrp + ((size_t)(hh * 128 + gg * 32 + r5)) * 8);
#pragma unroll
      for (int gg = 0; gg < 4; gg++)
        wq[1][gg] = ld8(wrp + ((size_t)((2 + hh) * 128 + gg * 32 + r5)) * 8);
      bf_cur = FRAG_ASM(zpk, 0, hh);
#pragma unroll
      for (int ks = 0; ks < 8; ks++) {
        if (ks + 2 < 8) {
#pragma unroll
          for (int gg = 0; gg < 4; gg++)
            wq[(ks + 2) % 3][gg] =
                ld8(wrp + ((size_t)((2 * (ks + 2) + hh) * 128 + gg * 32 + r5)) * 8);
        }
        bf8v bf_nxt = bf_cur;
        if (ks + 1 < 8) bf_nxt = FRAG_ASM(zpk, ks + 1, hh);
#pragma unroll
        for (int gg = 0; gg < 4; gg++) acc[gg] = mfma32(wq[ks % 3][gg], bf_cur, acc[gg]);
        bf_cur = bf_nxt;
      }
    }
    float s = 0.f, s2 = 0.f;
#pragma unroll
    for (int gg = 0; gg < 4; gg++)
#pragma unroll
      for (int wq4 = 0; wq4 < 4; wq4++) {
        int c0 = gg * 32 + wq4 * 8 + 4 * hh;
        float4 bv2 = *(const float4*)(eb2 + L * 128 + c0);
        float4 bvr = *(const float4*)(ebr + L * 128 + c0);
        acc[gg][wq4 * 4 + 0] += bv2.x + bvr.x;
        acc[gg][wq4 * 4 + 1] += bv2.y + bvr.y;
        acc[gg][wq4 * 4 + 2] += bv2.z + bvr.z;
        acc[gg][wq4 * 4 + 3] += bv2.w + bvr.w;
#pragma unroll
        for (int sidx = 0; sidx < 4; sidx++) {
          float v = acc[gg][wq4 * 4 + sidx];
          s += v; s2 += v * v;
        }
      }
    s += __shfl_xor(s, 32, 64); s2 += __shfl_xor(s2, 32, 64);
    float mean = s * (1.f / 128.f);
    float rstd = rsqrtf(s2 * (1.f / 128.f) - mean * mean + 1e-5f);
#pragma unroll
    for (int gg = 0; gg < 4; gg++)
#pragma unroll
      for (int wq4 = 0; wq4 < 4; wq4++) {
        int c0 = gg * 32 + wq4 * 8 + 4 * hh;
        float4 gv = *(const float4*)(eg + L * 128 + c0);
        float4 bv = *(const float4*)(ebe + L * 128 + c0);
        float v0 = (acc[gg][wq4 * 4 + 0] - mean) * rstd * gv.x + bv.x;
        float v1 = (acc[gg][wq4 * 4 + 1] - mean) * rstd * gv.y + bv.y;
        float v2 = (acc[gg][wq4 * 4 + 2] - mean) * rstd * gv.z + bv.z;
        float v3 = (acc[gg][wq4 * 4 + 3] - mean) * rstd * gv.w + bv.w;
        unsigned plo = pkbf2(v0, v1), phi = pkbf2(v2, v3);
        if (L == 0) {
          zpk[gg][wq4][0] = plo;
          zpk[gg][wq4][1] = phi;
        } else {
          uint2 pv = {plo, phi};
          *(uint2*)(zst + (w * 32 + r5) * 132 + c0) = pv;
        }
      }
  }

  // per-wave coalesced store of its own 32 rows (same-wave LDS RAW: no barrier)
#pragma unroll
  for (int it = 0; it < 8; it++) {
    int lu = it * 64 + lane;
    int rr = lu >> 4, seg = lu & 15;
    int orow = w * 32 + rr;
    *(uint4*)(zout + ((size_t)tile * 64 + orow) * 128 + seg * 8) =
        *(const uint4*)(zst + orow * 132 + seg * 8);
  }
}

// ---------------- K2: MultiHeadEMA (2-state scan) + residual + silu, IN-PLACE ----------------
__global__ __launch_bounds__(128) void k_ema(
    u16* __restrict__ z,
    const float* __restrict__ pdel, const float* __restrict__ palp,
    const float* __restrict__ pbet, const float* __restrict__ pgam,
    const float* __restrict__ pome) {
  __shared__ __align__(16) u16 zc[64 * 128];
  const int t = threadIdx.x;  // channel d
  const int bn = blockIdx.x;
  float p0 = 1.f / (1.f + __expf(-pdel[t * 2 + 0]));
  float p1 = 1.f / (1.f + __expf(-pdel[t * 2 + 1]));
  float q0 = 1.f - p0 / (1.f + __expf(-palp[t * 2 + 0]));
  float q1 = 1.f - p1 / (1.f + __expf(-palp[t * 2 + 1]));
  float w0 = p0 * pbet[t * 2 + 0] * pgam[t * 2 + 0] * EMA_SCALE;
  float w1 = p1 * pbet[t * 2 + 1] * pgam[t * 2 + 1] * EMA_SCALE;
  float om = pome[t];
  float s0 = 0.f, s1 = 0.f;
  u16* slab = z + (size_t)bn * KH;

  for (int ch = 0; ch < 4; ch++) {
    int nrow = (ch < 3) ? 64 : 63;
    int nval = nrow * 128;
    for (int i = t * 8; i < nval; i += 128 * 8)
      *(uint4*)(zc + i) = *(const uint4*)(slab + ch * 8192 + i);
    __syncthreads();
    for (int j0 = 0; j0 < nrow; j0 += 8) {
      float xs[8];
#pragma unroll
      for (int jj = 0; jj < 8; jj++)
        if (j0 + jj < nrow) xs[jj] = bf2f(zc[(j0 + jj) * 128 + t]);
#pragma unroll
      for (int jj = 0; jj < 8; jj++)
        if (j0 + jj < nrow) {
          float xv = xs[jj];
          s0 = q0 * s0 + xv;
          s1 = q1 * s1 + xv;
          float v = w0 * s0 + w1 * s1 + om * xv;
          xs[jj] = v / (1.f + __expf(-v));  // silu
        }
#pragma unroll
      for (int jj = 0; jj < 8; jj++)
        if (j0 + jj < nrow)
          zc[(j0 + jj) * 128 + t] = (u16)((__float_as_uint(xs[jj]) + 0x8000u) >> 16);
    }
    __syncthreads();
    for (int i = t * 8; i < nval; i += 128 * 8)
      *(uint4*)(slab + ch * 8192 + i) = *(const uint4*)(zc + i);
    __syncthreads();
  }
}

// ---------------- K3: head GEMM partials (K split into 30 chunks of 1088) ----------------
__global__ __launch_bounds__(256) void k_head(
    const u16* __restrict__ u, const u16* __restrict__ whs, float* __restrict__ part) {
  const int t = threadIdx.x;
  const int lane = t & 63, wid = t >> 6;
  const int quad = lane >> 4, lc = lane & 15;
  const int tile = blockIdx.x;  // 0..20
  const int ch = blockIdx.y;    // 0..29
  const int m0 = tile * 64 + wid * 16;
  const u16* Ab = u + (size_t)(m0 + lc) * KH + (size_t)ch * KPC;
  const int g0 = ch * (KPC / 8);  // base k-group
  f4v acc[6];
#pragma unroll
  for (int n = 0; n < 6; n++) acc[n] = (f4v){0.f, 0.f, 0.f, 0.f};
  bf8v a_nxt = ld8(Ab + quad * 8);
  bf8v b_nxt[6];
#pragma unroll
  for (int n = 0; n < 6; n++)
    b_nxt[n] = ld8(whs + ((size_t)(g0 + quad) * PRED + n * 16 + lc) * 8);
  for (int ks = 0; ks < HITER; ks++) {
    bf8v a_cur = a_nxt;
    bf8v b_cur[6];
#pragma unroll
    for (int n = 0; n < 6; n++) b_cur[n] = b_nxt[n];
    if (ks < HITER - 1) {
      a_nxt = ld8(Ab + (ks + 1) * 32 + quad * 8);
#pragma unroll
      for (int n = 0; n < 6; n++)
        b_nxt[n] = ld8(whs + ((size_t)(g0 + (ks + 1) * 4 + quad) * PRED + n * 16 + lc) * 8);
    }
#pragma unroll
    for (int n = 0; n < 6; n++) acc[n] = mfma16(a_cur, b_cur[n], acc[n]);
  }
#pragma unroll
  for (int n = 0; n < 6; n++) {
    int col = n * 16 + lc;
#pragma unroll
    for (int r = 0; r < 4; r++)
      part[((size_t)ch * BN + m0 + quad * 4 + r) * PRED + col] = acc[n][r];
  }
}

// ---------------- K4: reduce partials + bias -> fp32 out ----------------
__global__ __launch_bounds__(256) void k_red(
    const float* __restrict__ part, const float* __restrict__ hb, float* __restrict__ out) {
  int i = blockIdx.x * 256 + threadIdx.x;
  if (i >= BN * PRED) return;
  int row = i / PRED, col = i - row * PRED;
  float s = hb[col];
#pragma unroll 5
  for (int c = 0; c < CH; c++) s += part[((size_t)c * BN + row) * PRED + col];
  out[i] = s;
}

// ---------------- host ----------------
extern "C" void kernel_launch(void* const* d_in, const int* in_sizes, int n_in,
                              void* d_out, int out_size, void* d_ws, size_t ws_size,
                              hipStream_t stream) {
  const float* x      = (const float*)d_in[0];
  const float* fp_w1  = (const float*)d_in[1];
  const float* fp_b1  = (const float*)d_in[2];
  const float* fp_w2  = (const float*)d_in[3];
  const float* fp_b2  = (const float*)d_in[4];
  const float* fp_wr  = (const float*)d_in[5];
  const float* fp_br  = (const float*)d_in[6];
  const float* fp_g   = (const float*)d_in[7];
  const float* fp_be  = (const float*)d_in[8];
  const float* enc_w1 = (const float*)d_in[9];
  const float* enc_b1 = (const float*)d_in[10];
  const float* enc_w2 = (const float*)d_in[11];
  const float* enc_b2 = (const float*)d_in[12];
  const float* enc_wr = (const float*)d_in[13];
  const float* enc_br = (const float*)d_in[14];
  const float* enc_g  = (const float*)d_in[15];
  const float* enc_be = (const float*)d_in[16];
  const float* e_del  = (const float*)d_in[17];
  const float* e_alp  = (const float*)d_in[18];
  const float* e_bet  = (const float*)d_in[19];
  const float* e_gam  = (const float*)d_in[20];
  const float* e_om   = (const float*)d_in[21];
  const float* head_w = (const float*)d_in[22];
  const float* head_b = (const float*)d_in[23];

  // ws layout (bytes):
  //   [0, 87736320)             z3 / u  (bf16, [ROWS][128])
  //   [87736320, 103219200)     part    (fp32, [30][1344][96])
  //   [103219200, ...)          swizzled bf16 weights (~6.6 MB)
  char* base = (char*)d_ws;
  u16* z3 = (u16*)base;
  const size_t EZB = (size_t)ROWS * 128 * 2;        // 87,736,320
  float* part = (float*)(base + EZB);
  const size_t PARTB = (size_t)CH * BN * PRED * 4;  // 15,482,880
  u16* wb = (u16*)(base + EZB + PARTB);
  // wb offsets (u16): ws1=0(8192), ws2=8192(32768), wsr=40960(4096),
  //                   wse=45056(6*16384), wsh=143360(32640*96)
  u16* ws1 = wb;
  u16* ws2 = wb + 8192;
  u16* wsr = wb + 40960;
  u16* wse = wb + 45056;
  u16* wsh = wb + 143360;

  swz_all<<<560 + (KH * PRED + 255) / 256, 256, 0, stream>>>(
      fp_w1, fp_w2, fp_wr, enc_w1, enc_w2, enc_wr, head_w, wb, wsh);

  k_lem<<<ROWS / 64, 128, 0, stream>>>(x, ws1, fp_b1, ws2, wsr, fp_b2, fp_br, fp_g, fp_be,
                                       wse, enc_b1, enc_b2, enc_br, enc_g, enc_be, z3);
  k_ema<<<BN, 128, 0, stream>>>(z3, e_del, e_alp, e_bet, e_gam, e_om);
  k_head<<<dim3(21, CH), 256, 0, stream>>>(z3, wsh, part);
  k_red<<<(BN * PRED + 255) / 256, 256, 0, stream>>>(part, head_b, (float*)d_out);
}

// Round 5
// 419.713 us; speedup vs baseline: 1.2587x; 1.1022x over previous
//
#include <hip/hip_runtime.h>

typedef unsigned short u16;
typedef short bf8v __attribute__((ext_vector_type(8)));
typedef float f4v __attribute__((ext_vector_type(4)));
typedef float f16v __attribute__((ext_vector_type(16)));

#define DEV static __device__ __forceinline__

constexpr int BB   = 64;
constexpr int NV   = 21;
constexpr int BN   = BB * NV;       // 1344
constexpr int PNUM = 255;
constexpr int D    = 128;
constexpr int PRED = 96;
constexpr int ROWS = BN * PNUM;     // 342720 = 64 * 5355
constexpr int KH   = D * PNUM;      // 32640 head K
constexpr int CH   = 30;            // head K chunks
constexpr int KPC  = KH / CH;       // 1088 = 34*32
constexpr int HITER = KPC / 32;     // 34
constexpr float EMA_SCALE = 0.70710678118654752440f;  // 1/sqrt(2)

DEV float bf2f(u16 h) { return __uint_as_float(((unsigned)h) << 16); }
DEV u16 f2bf(float f) {  // RNE (weight prepass only)
  unsigned u = __float_as_uint(f);
  return (u16)((u + 0x7fffu + ((u >> 16) & 1u)) >> 16);
}
// pack two floats to bf16 pair (round-half-up): lo = a, hi = b
DEV unsigned pkbf2(float a, float b) {
  unsigned ua = __float_as_uint(a) + 0x8000u;
  unsigned ub = __float_as_uint(b) + 0x8000u;
  return __builtin_amdgcn_perm(ub, ua, 0x07060302u);
}
DEV bf8v mk4(unsigned a, unsigned b, unsigned c, unsigned d) {
  int4 t = {(int)a, (int)b, (int)c, (int)d};
  bf8v r;
  __builtin_memcpy(&r, &t, 16);
  return r;
}
DEV bf8v ld8(const u16* p) {
  bf8v r;
  __builtin_memcpy(&r, p, 16);
  return r;
}
DEV f4v mfma16(bf8v a, bf8v b, f4v c) {
  return __builtin_amdgcn_mfma_f32_16x16x32_bf16(a, b, c, 0, 0, 0);
}
DEV f16v mfma32(bf8v a, bf8v b, f16v c) {
  return __builtin_amdgcn_mfma_f32_32x32x16_bf16(a, b, c, 0, 0, 0);
}
DEV f16v zero16() {
  f16v r;
#pragma unroll
  for (int i = 0; i < 16; i++) r[i] = 0.f;
  return r;
}

// Assemble B-operand fragment (8 contiguous channels [16*ks+8*hh .. +7] of this
// lane's row) from packed D-layout register array pk[g][w][2] via one
// shfl_xor(32) pair exchange. Loops calling this are fully unrolled, so the
// indices are compile-time constants post-unroll (SROA keeps pk in registers).
// NOTE (r1-r4 probes): permlane variant, 3-buffer prefetch, and group fusion
// all REGRESS this kernel (codegen/register effects dominate); this exact
// structure is a sharp local optimum at 128 arch VGPR + 64 AGPR, 2 waves/SIMD.
#define FRAG_ASM(pk, ks, hh)                                                   \
  ({                                                                           \
    int _g = (ks) >> 1, _lw = 2 * ((ks) & 1);                                  \
    unsigned _A0 = pk[_g][_lw][0], _A1 = pk[_g][_lw][1];                       \
    unsigned _B0 = pk[_g][_lw + 1][0], _B1 = pk[_g][_lw + 1][1];               \
    unsigned _own0 = (hh) ? _B0 : _A0, _own1 = (hh) ? _B1 : _A1;               \
    unsigned _snd0 = (hh) ? _A0 : _B0, _snd1 = (hh) ? _A1 : _B1;               \
    unsigned _o0 = (unsigned)__shfl_xor((int)_snd0, 32, 64);                   \
    unsigned _o1 = (unsigned)__shfl_xor((int)_snd1, 32, 64);                   \
    mk4((hh) ? _o0 : _own0, (hh) ? _o1 : _own1,                                \
        (hh) ? _own0 : _o0, (hh) ? _own1 : _o1);                               \
  })

// ---------------- fused weight swizzle prepass (fp32 -> bf16 fragments) ----------------
// frag[((k>>3)*N + n)*8 + (k&7)] = src[k*N + n]; k >= K zero-filled.
__global__ void swz_all(
    const float* __restrict__ fw1, const float* __restrict__ fw2,
    const float* __restrict__ fwr, const float* __restrict__ ew1,
    const float* __restrict__ ew2, const float* __restrict__ ewr,
    const float* __restrict__ hw, u16* __restrict__ wb, u16* __restrict__ wsh) {
  int b = blockIdx.x;
  if (b >= 560) {  // head_w [d*255+l][96] -> fragments in k-order kp = l*128 + d
    int i = (b - 560) * 256 + threadIdx.x;
    if (i >= KH * PRED) return;
    int kp = i / PRED, n = i - kp * PRED;
    int l = kp >> 7, d = kp & 127;
    wsh[((size_t)(kp >> 3) * PRED + n) * 8 + (kp & 7)] =
        f2bf(hw[(size_t)(d * PNUM + l) * PRED + n]);
    return;
  }
  const float* src; u16* dst; int K, N, Kp;
  if (b < 32)       { src = fw1; dst = wb;          K = 16;  N = 256; Kp = 32; }
  else if (b < 160) { b -= 32;  src = fw2; dst = wb + 8192;  K = 256; N = 128; Kp = 256; }
  else if (b < 176) { b -= 160; src = fwr; dst = wb + 40960; K = 16;  N = 128; Kp = 32; }
  else {
    int e = (b - 176) >> 6; b = (b - 176) & 63;
    int l = e / 3, w = e - 3 * l;
    const float* basep = (w == 0) ? ew1 : (w == 1) ? ew2 : ewr;
    src = basep + (size_t)l * 16384;
    dst = wb + 45056 + e * 16384;
    K = 128; N = 128; Kp = 128;
  }
  int i = b * 256 + threadIdx.x;
  if (i >= Kp * N) return;
  int k = i / N, n = i - k * N;
  u16 v = (k < K) ? f2bf(src[(size_t)k * N + n]) : (u16)0;
  dst[((size_t)(k >> 3) * N + n) * 8 + (k & 7)] = v;
}

// ---------------- K1: fused gather + fp LEMblock + 2 encoder LEMblocks ----------------
// 32x32x16 MFMA, transposed (A=weight, B=act). Each wave owns 32 rows; lane's
// act-row = lane&31. Between-GEMM relayout done IN REGISTERS via shfl_xor(32)
// (no act LDS, no barriers). LDS only stages the final 64x128 output tile.
// EXACT r0 structure (proven 200us / 384us total).
__global__ __launch_bounds__(128, 2) void k_lem(
    const float* __restrict__ x,
    const u16* __restrict__ ws1, const float* __restrict__ b1,
    const u16* __restrict__ ws2, const u16* __restrict__ wsr,
    const float* __restrict__ b2, const float* __restrict__ br,
    const float* __restrict__ g, const float* __restrict__ be,
    const u16* __restrict__ wse, const float* __restrict__ eb1,
    const float* __restrict__ eb2, const float* __restrict__ ebr,
    const float* __restrict__ eg, const float* __restrict__ ebe,
    u16* __restrict__ zout) {
  __shared__ __align__(16) u16 zst[64 * 132];
  const int t = threadIdx.x;
  const int lane = t & 63, w = t >> 6;  // w: wave 0..1
  const int hh = lane >> 5, r5 = lane & 31;
  const int tile = blockIdx.x;
  const int row = tile * 64 + w * 32 + r5;

  // gather z0: lane holds patch elems [8*hh .. 8*hh+7] of its row (B-frag K=16)
  bf8v azv;
  {
    unsigned R = (unsigned)row;
    unsigned bn = R / 255u;
    unsigned p = R - bn * 255u;
    const float* px = x + (size_t)bn * 2048u + p * 8u + hh * 8;
    float4 v0 = *(const float4*)px;
    float4 v1 = *(const float4*)(px + 4);
    azv = mk4(pkbf2(v0.x, v0.y), pkbf2(v0.z, v0.w),
              pkbf2(v1.x, v1.y), pkbf2(v1.z, v1.w));
  }

  unsigned hpk[8][4][2];  // packed h (256 chans, D-layout halves)
  unsigned zpk[4][4][2];  // packed z (128 chans)

  // ---- GEMM1: h = relu(W1^T z0 + b1), two halves of 128 cols ----
#pragma unroll
  for (int half = 0; half < 2; half++) {
    f16v a[4];
#pragma unroll
    for (int gg = 0; gg < 4; gg++) {
      bf8v wf = ld8(ws1 + ((size_t)(hh * 256 + (half * 4 + gg) * 32 + r5)) * 8);
      a[gg] = mfma32(wf, azv, zero16());
    }
#pragma unroll
    for (int gg = 0; gg < 4; gg++)
#pragma unroll
      for (int wq = 0; wq < 4; wq++) {
        int c0 = (half * 4 + gg) * 32 + wq * 8 + 4 * hh;
        float4 bv = *(const float4*)(b1 + c0);
        float v0 = fmaxf(a[gg][wq * 4 + 0] + bv.x, 0.f);
        float v1 = fmaxf(a[gg][wq * 4 + 1] + bv.y, 0.f);
        float v2 = fmaxf(a[gg][wq * 4 + 2] + bv.z, 0.f);
        float v3 = fmaxf(a[gg][wq * 4 + 3] + bv.w, 0.f);
        hpk[half * 4 + gg][wq][0] = pkbf2(v0, v1);
        hpk[half * 4 + gg][wq][1] = pkbf2(v2, v3);
      }
  }

  // ---- GEMM2: y1 = W2^T h + Wr^T z0 + b2 + br -> LN -> z1 ----
  {
    f16v acc[4];
#pragma unroll
    for (int gg = 0; gg < 4; gg++) {
      bf8v wf = ld8(wsr + ((size_t)(hh * 128 + gg * 32 + r5)) * 8);
      acc[gg] = mfma32(wf, azv, zero16());
    }
    bf8v wq[2][4];
#pragma unroll
    for (int gg = 0; gg < 4; gg++)
      wq[0][gg] = ld8(ws2 + ((size_t)(hh * 128 + gg * 32 + r5)) * 8);
    bf8v bf_cur = FRAG_ASM(hpk, 0, hh);
#pragma unroll
    for (int ks = 0; ks < 16; ks++) {
      int cur = ks & 1;
      if (ks < 15) {
#pragma unroll
        for (int gg = 0; gg < 4; gg++)
          wq[cur ^ 1][gg] =
              ld8(ws2 + ((size_t)((2 * (ks + 1) + hh) * 128 + gg * 32 + r5)) * 8);
        bf8v bf_nxt = FRAG_ASM(hpk, ks + 1, hh);
#pragma unroll
        for (int gg = 0; gg < 4; gg++) acc[gg] = mfma32(wq[cur][gg], bf_cur, acc[gg]);
        bf_cur = bf_nxt;
      } else {
#pragma unroll
        for (int gg = 0; gg < 4; gg++) acc[gg] = mfma32(wq[cur][gg], bf_cur, acc[gg]);
      }
    }
    // bias + LN
    float s = 0.f, s2 = 0.f;
#pragma unroll
    for (int gg = 0; gg < 4; gg++)
#pragma unroll
      for (int wq4 = 0; wq4 < 4; wq4++) {
        int c0 = gg * 32 + wq4 * 8 + 4 * hh;
        float4 bv2 = *(const float4*)(b2 + c0);
        float4 bvr = *(const float4*)(br + c0);
        acc[gg][wq4 * 4 + 0] += bv2.x + bvr.x;
        acc[gg][wq4 * 4 + 1] += bv2.y + bvr.y;
        acc[gg][wq4 * 4 + 2] += bv2.z + bvr.z;
        acc[gg][wq4 * 4 + 3] += bv2.w + bvr.w;
#pragma unroll
        for (int sidx = 0; sidx < 4; sidx++) {
          float v = acc[gg][wq4 * 4 + sidx];
          s += v; s2 += v * v;
        }
      }
    s += __shfl_xor(s, 32, 64); s2 += __shfl_xor(s2, 32, 64);
    float mean = s * (1.f / 128.f);
    float rstd = rsqrtf(s2 * (1.f / 128.f) - mean * mean + 1e-5f);
#pragma unroll
    for (int gg = 0; gg < 4; gg++)
#pragma unroll
      for (int wq4 = 0; wq4 < 4; wq4++) {
        int c0 = gg * 32 + wq4 * 8 + 4 * hh;
        float4 gv = *(const float4*)(g + c0);
        float4 bv = *(const float4*)(be + c0);
        float v0 = (acc[gg][wq4 * 4 + 0] - mean) * rstd * gv.x + bv.x;
        float v1 = (acc[gg][wq4 * 4 + 1] - mean) * rstd * gv.y + bv.y;
        float v2 = (acc[gg][wq4 * 4 + 2] - mean) * rstd * gv.z + bv.z;
        float v3 = (acc[gg][wq4 * 4 + 3] - mean) * rstd * gv.w + bv.w;
        zpk[gg][wq4][0] = pkbf2(v0, v1);
        zpk[gg][wq4][1] = pkbf2(v2, v3);
      }
  }

  // ---- encoder layers ----
#pragma unroll 1
  for (int L = 0; L < 2; L++) {
    const u16* w1p = wse + (size_t)(L * 3 + 0) * 16384;
    const u16* w2p = wse + (size_t)(L * 3 + 1) * 16384;
    const u16* wrp = wse + (size_t)(L * 3 + 2) * 16384;
    unsigned hp2[4][4][2];
    // GEMM-A: h2 = relu(W1^T z + eb1)
    {
      f16v a2[4];
#pragma unroll
      for (int gg = 0; gg < 4; gg++) a2[gg] = zero16();
      bf8v wq[2][4];
#pragma unroll
      for (int gg = 0; gg < 4; gg++)
        wq[0][gg] = ld8(w1p + ((size_t)(hh * 128 + gg * 32 + r5)) * 8);
      bf8v bf_cur = FRAG_ASM(zpk, 0, hh);
#pragma unroll
      for (int ks = 0; ks < 8; ks++) {
        int cur = ks & 1;
        if (ks < 7) {
#pragma unroll
          for (int gg = 0; gg < 4; gg++)
            wq[cur ^ 1][gg] =
                ld8(w1p + ((size_t)((2 * (ks + 1) + hh) * 128 + gg * 32 + r5)) * 8);
          bf8v bf_nxt = FRAG_ASM(zpk, ks + 1, hh);
#pragma unroll
          for (int gg = 0; gg < 4; gg++) a2[gg] = mfma32(wq[cur][gg], bf_cur, a2[gg]);
          bf_cur = bf_nxt;
        } else {
#pragma unroll
          for (int gg = 0; gg < 4; gg++) a2[gg] = mfma32(wq[cur][gg], bf_cur, a2[gg]);
        }
      }
#pragma unroll
      for (int gg = 0; gg < 4; gg++)
#pragma unroll
        for (int wq4 = 0; wq4 < 4; wq4++) {
          int c0 = gg * 32 + wq4 * 8 + 4 * hh;
          float4 bv = *(const float4*)(eb1 + L * 128 + c0);
          float v0 = fmaxf(a2[gg][wq4 * 4 + 0] + bv.x, 0.f);
          float v1 = fmaxf(a2[gg][wq4 * 4 + 1] + bv.y, 0.f);
          float v2 = fmaxf(a2[gg][wq4 * 4 + 2] + bv.z, 0.f);
          float v3 = fmaxf(a2[gg][wq4 * 4 + 3] + bv.w, 0.f);
          hp2[gg][wq4][0] = pkbf2(v0, v1);
          hp2[gg][wq4][1] = pkbf2(v2, v3);
        }
    }
    // GEMM-B: y = W2^T h2 + Wr^T z + biases -> LN
    f16v acc[4];
#pragma unroll
    for (int gg = 0; gg < 4; gg++) acc[gg] = zero16();
    {
      bf8v wq[2][4];
#pragma unroll
      for (int gg = 0; gg < 4; gg++)
        wq[0][gg] = ld8(w2p + ((size_t)(hh * 128 + gg * 32 + r5)) * 8);
      bf8v bf_cur = FRAG_ASM(hp2, 0, hh);
#pragma unroll
      for (int ks = 0; ks < 8; ks++) {
        int cur = ks & 1;
        if (ks < 7) {
#pragma unroll
          for (int gg = 0; gg < 4; gg++)
            wq[cur ^ 1][gg] =
                ld8(w2p + ((size_t)((2 * (ks + 1) + hh) * 128 + gg * 32 + r5)) * 8);
          bf8v bf_nxt = FRAG_ASM(hp2, ks + 1, hh);
#pragma unroll
          for (int gg = 0; gg < 4; gg++) acc[gg] = mfma32(wq[cur][gg], bf_cur, acc[gg]);
          bf_cur = bf_nxt;
        } else {
#pragma unroll
          for (int gg = 0; gg < 4; gg++) acc[gg] = mfma32(wq[cur][gg], bf_cur, acc[gg]);
        }
      }
#pragma unroll
      for (int gg = 0; gg < 4; gg++)
        wq[0][gg] = ld8(wrp + ((size_t)(hh * 128 + gg * 32 + r5)) * 8);
      bf_cur = FRAG_ASM(zpk, 0, hh);
#pragma unroll
      for (int ks = 0; ks < 8; ks++) {
        int cur = ks & 1;
        if (ks < 7) {
#pragma unroll
          for (int gg = 0; gg < 4; gg++)
            wq[cur ^ 1][gg] =
                ld8(wrp + ((size_t)((2 * (ks + 1) + hh) * 128 + gg * 32 + r5)) * 8);
          bf8v bf_nxt = FRAG_ASM(zpk, ks + 1, hh);
#pragma unroll
          for (int gg = 0; gg < 4; gg++) acc[gg] = mfma32(wq[cur][gg], bf_cur, acc[gg]);
          bf_cur = bf_nxt;
        } else {
#pragma unroll
          for (int gg = 0; gg < 4; gg++) acc[gg] = mfma32(wq[cur][gg], bf_cur, acc[gg]);
        }
      }
    }
    float s = 0.f, s2 = 0.f;
#pragma unroll
    for (int gg = 0; gg < 4; gg++)
#pragma unroll
      for (int wq4 = 0; wq4 < 4; wq4++) {
        int c0 = gg * 32 + wq4 * 8 + 4 * hh;
        float4 bv2 = *(const float4*)(eb2 + L * 128 + c0);
        float4 bvr = *(const float4*)(ebr + L * 128 + c0);
        acc[gg][wq4 * 4 + 0] += bv2.x + bvr.x;
        acc[gg][wq4 * 4 + 1] += bv2.y + bvr.y;
        acc[gg][wq4 * 4 + 2] += bv2.z + bvr.z;
        acc[gg][wq4 * 4 + 3] += bv2.w + bvr.w;
#pragma unroll
        for (int sidx = 0; sidx < 4; sidx++) {
          float v = acc[gg][wq4 * 4 + sidx];
          s += v; s2 += v * v;
        }
      }
    s += __shfl_xor(s, 32, 64); s2 += __shfl_xor(s2, 32, 64);
    float mean = s * (1.f / 128.f);
    float rstd = rsqrtf(s2 * (1.f / 128.f) - mean * mean + 1e-5f);
#pragma unroll
    for (int gg = 0; gg < 4; gg++)
#pragma unroll
      for (int wq4 = 0; wq4 < 4; wq4++) {
        int c0 = gg * 32 + wq4 * 8 + 4 * hh;
        float4 gv = *(const float4*)(eg + L * 128 + c0);
        float4 bv = *(const float4*)(ebe + L * 128 + c0);
        float v0 = (acc[gg][wq4 * 4 + 0] - mean) * rstd * gv.x + bv.x;
        float v1 = (acc[gg][wq4 * 4 + 1] - mean) * rstd * gv.y + bv.y;
        float v2 = (acc[gg][wq4 * 4 + 2] - mean) * rstd * gv.z + bv.z;
        float v3 = (acc[gg][wq4 * 4 + 3] - mean) * rstd * gv.w + bv.w;
        unsigned plo = pkbf2(v0, v1), phi = pkbf2(v2, v3);
        if (L == 0) {
          zpk[gg][wq4][0] = plo;
          zpk[gg][wq4][1] = phi;
        } else {
          uint2 pv = {plo, phi};
          *(uint2*)(zst + (w * 32 + r5) * 132 + c0) = pv;
        }
      }
  }

  // per-wave coalesced store of its own 32 rows (same-wave LDS RAW: no barrier)
#pragma unroll
  for (int it = 0; it < 8; it++) {
    int lu = it * 64 + lane;
    int rr = lu >> 4, seg = lu & 15;
    int orow = w * 32 + rr;
    *(uint4*)(zout + ((size_t)tile * 64 + orow) * 128 + seg * 8) =
        *(const uint4*)(zst + orow * 132 + seg * 8);
  }
}

// ---------------- K2: MultiHeadEMA (2-state scan) + residual + silu, IN-PLACE ----------------
// r5: double-buffered LDS (32KB) -- chunk ch+1's global->LDS load issues
// before the chunk-ch scan, hiding load latency under scan VALU; 2 barriers
// per chunk instead of 3.
__global__ __launch_bounds__(128) void k_ema(
    u16* __restrict__ z,
    const float* __restrict__ pdel, const float* __restrict__ palp,
    const float* __restrict__ pbet, const float* __restrict__ pgam,
    const float* __restrict__ pome) {
  __shared__ __align__(16) u16 zc[2][64 * 128];
  const int t = threadIdx.x;  // channel d
  const int bn = blockIdx.x;
  float p0 = 1.f / (1.f + __expf(-pdel[t * 2 + 0]));
  float p1 = 1.f / (1.f + __expf(-pdel[t * 2 + 1]));
  float q0 = 1.f - p0 / (1.f + __expf(-palp[t * 2 + 0]));
  float q1 = 1.f - p1 / (1.f + __expf(-palp[t * 2 + 1]));
  float w0 = p0 * pbet[t * 2 + 0] * pgam[t * 2 + 0] * EMA_SCALE;
  float w1 = p1 * pbet[t * 2 + 1] * pgam[t * 2 + 1] * EMA_SCALE;
  float om = pome[t];
  float s0 = 0.f, s1 = 0.f;
  u16* slab = z + (size_t)bn * KH;

  // preload chunk 0
  for (int i = t * 8; i < 64 * 128; i += 128 * 8)
    *(uint4*)(&zc[0][i]) = *(const uint4*)(slab + i);

  for (int ch = 0; ch < 4; ch++) {
    int nrow = (ch < 3) ? 64 : 63;
    int nval = nrow * 128;
    u16* buf = zc[ch & 1];
    __syncthreads();  // load(ch) visible; store(ch-1) LDS-reads drained
    if (ch < 3) {     // prefetch chunk ch+1 into the other buffer
      int nv2 = ((ch + 1 < 3) ? 64 : 63) * 128;
      u16* nbuf = zc[(ch + 1) & 1];
      for (int i = t * 8; i < nv2; i += 128 * 8)
        *(uint4*)(nbuf + i) = *(const uint4*)(slab + (ch + 1) * 8192 + i);
    }
    for (int j0 = 0; j0 < nrow; j0 += 8) {
      float xs[8];
#pragma unroll
      for (int jj = 0; jj < 8; jj++)
        if (j0 + jj < nrow) xs[jj] = bf2f(buf[(j0 + jj) * 128 + t]);
#pragma unroll
      for (int jj = 0; jj < 8; jj++)
        if (j0 + jj < nrow) {
          float xv = xs[jj];
          s0 = q0 * s0 + xv;
          s1 = q1 * s1 + xv;
          float v = w0 * s0 + w1 * s1 + om * xv;
          xs[jj] = v / (1.f + __expf(-v));  // silu
        }
#pragma unroll
      for (int jj = 0; jj < 8; jj++)
        if (j0 + jj < nrow)
          buf[(j0 + jj) * 128 + t] = (u16)((__float_as_uint(xs[jj]) + 0x8000u) >> 16);
    }
    __syncthreads();  // scan writes visible to store's readers
    for (int i = t * 8; i < nval; i += 128 * 8)
      *(uint4*)(slab + ch * 8192 + i) = *(const uint4*)(buf + i);
  }
}

// ---------------- K3: head GEMM partials (K split into 30 chunks of 1088) ----------------
__global__ __launch_bounds__(256) void k_head(
    const u16* __restrict__ u, const u16* __restrict__ whs, float* __restrict__ part) {
  const int t = threadIdx.x;
  const int lane = t & 63, wid = t >> 6;
  const int quad = lane >> 4, lc = lane & 15;
  const int tile = blockIdx.x;  // 0..20
  const int ch = blockIdx.y;    // 0..29
  const int m0 = tile * 64 + wid * 16;
  const u16* Ab = u + (size_t)(m0 + lc) * KH + (size_t)ch * KPC;
  const int g0 = ch * (KPC / 8);  // base k-group
  f4v acc[6];
#pragma unroll
  for (int n = 0; n < 6; n++) acc[n] = (f4v){0.f, 0.f, 0.f, 0.f};
  bf8v a_nxt = ld8(Ab + quad * 8);
  bf8v b_nxt[6];
#pragma unroll
  for (int n = 0; n < 6; n++)
    b_nxt[n] = ld8(whs + ((size_t)(g0 + quad) * PRED + n * 16 + lc) * 8);
  for (int ks = 0; ks < HITER; ks++) {
    bf8v a_cur = a_nxt;
    bf8v b_cur[6];
#pragma unroll
    for (int n = 0; n < 6; n++) b_cur[n] = b_nxt[n];
    if (ks < HITER - 1) {
      a_nxt = ld8(Ab + (ks + 1) * 32 + quad * 8);
#pragma unroll
      for (int n = 0; n < 6; n++)
        b_nxt[n] = ld8(whs + ((size_t)(g0 + (ks + 1) * 4 + quad) * PRED + n * 16 + lc) * 8);
    }
#pragma unroll
    for (int n = 0; n < 6; n++) acc[n] = mfma16(a_cur, b_cur[n], acc[n]);
  }
#pragma unroll
  for (int n = 0; n < 6; n++) {
    int col = n * 16 + lc;
#pragma unroll
    for (int r = 0; r < 4; r++)
      part[((size_t)ch * BN + m0 + quad * 4 + r) * PRED + col] = acc[n][r];
  }
}

// ---------------- K4: reduce partials + bias -> fp32 out ----------------
__global__ __launch_bounds__(256) void k_red(
    const float* __restrict__ part, const float* __restrict__ hb, float* __restrict__ out) {
  int i = blockIdx.x * 256 + threadIdx.x;
  if (i >= BN * PRED) return;
  int row = i / PRED, col = i - row * PRED;
  float s = hb[col];
#pragma unroll 5
  for (int c = 0; c < CH; c++) s += part[((size_t)c * BN + row) * PRED + col];
  out[i] = s;
}

// ---------------- host ----------------
extern "C" void kernel_launch(void* const* d_in, const int* in_sizes, int n_in,
                              void* d_out, int out_size, void* d_ws, size_t ws_size,
                              hipStream_t stream) {
  const float* x      = (const float*)d_in[0];
  const float* fp_w1  = (const float*)d_in[1];
  const float* fp_b1  = (const float*)d_in[2];
  const float* fp_w2  = (const float*)d_in[3];
  const float* fp_b2  = (const float*)d_in[4];
  const float* fp_wr  = (const float*)d_in[5];
  const float* fp_br  = (const float*)d_in[6];
  const float* fp_g   = (const float*)d_in[7];
  const float* fp_be  = (const float*)d_in[8];
  const float* enc_w1 = (const float*)d_in[9];
  const float* enc_b1 = (const float*)d_in[10];
  const float* enc_w2 = (const float*)d_in[11];
  const float* enc_b2 = (const float*)d_in[12];
  const float* enc_wr = (const float*)d_in[13];
  const float* enc_br = (const float*)d_in[14];
  const float* enc_g  = (const float*)d_in[15];
  const float* enc_be = (const float*)d_in[16];
  const float* e_del  = (const float*)d_in[17];
  const float* e_alp  = (const float*)d_in[18];
  const float* e_bet  = (const float*)d_in[19];
  const float* e_gam  = (const float*)d_in[20];
  const float* e_om   = (const float*)d_in[21];
  const float* head_w = (const float*)d_in[22];
  const float* head_b = (const float*)d_in[23];

  // ws layout (bytes):
  //   [0, 87736320)             z3 / u  (bf16, [ROWS][128])
  //   [87736320, 103219200)     part    (fp32, [30][1344][96])
  //   [103219200, ...)          swizzled bf16 weights (~6.6 MB)
  char* base = (char*)d_ws;
  u16* z3 = (u16*)base;
  const size_t EZB = (size_t)ROWS * 128 * 2;        // 87,736,320
  float* part = (float*)(base + EZB);
  const size_t PARTB = (size_t)CH * BN * PRED * 4;  // 15,482,880
  u16* wb = (u16*)(base + EZB + PARTB);
  // wb offsets (u16): ws1=0(8192), ws2=8192(32768), wsr=40960(4096),
  //                   wse=45056(6*16384), wsh=143360(32640*96)
  u16* ws1 = wb;
  u16* ws2 = wb + 8192;
  u16* wsr = wb + 40960;
  u16* wse = wb + 45056;
  u16* wsh = wb + 143360;

  swz_all<<<560 + (KH * PRED + 255) / 256, 256, 0, stream>>>(
      fp_w1, fp_w2, fp_wr, enc_w1, enc_w2, enc_wr, head_w, wb, wsh);

  k_lem<<<ROWS / 64, 128, 0, stream>>>(x, ws1, fp_b1, ws2, wsr, fp_b2, fp_br, fp_g, fp_be,
                                       wse, enc_b1, enc_b2, enc_br, enc_g, enc_be, z3);
  k_ema<<<BN, 128, 0, stream>>>(z3, e_del, e_alp, e_bet, e_gam, e_om);
  k_head<<<dim3(21, CH), 256, 0, stream>>>(z3, wsh, part);
  k_red<<<(BN * PRED + 255) / 256, 256, 0, stream>>>(part, head_b, (float*)d_out);
}

// Round 6
// 392.813 us; speedup vs baseline: 1.3449x; 1.0685x over previous
//
#include <hip/hip_runtime.h>

typedef unsigned short u16;
typedef short bf8v __attribute__((ext_vector_type(8)));
typedef float f4v __attribute__((ext_vector_type(4)));
typedef float f16v __attribute__((ext_vector_type(16)));

#define DEV static __device__ __forceinline__

constexpr int BB   = 64;
constexpr int NV   = 21;
constexpr int BN   = BB * NV;       // 1344
constexpr int PNUM = 255;
constexpr int D    = 128;
constexpr int PRED = 96;
constexpr int ROWS = BN * PNUM;     // 342720 = 64 * 5355
constexpr int KH   = D * PNUM;      // 32640 head K
constexpr int CH   = 30;            // head K chunks
constexpr int KPC  = KH / CH;       // 1088 = 34*32
constexpr int HITER = KPC / 32;     // 34
constexpr float EMA_SCALE = 0.70710678118654752440f;  // 1/sqrt(2)

DEV float bf2f(u16 h) { return __uint_as_float(((unsigned)h) << 16); }
DEV u16 f2bf(float f) {  // RNE (weight prepass only)
  unsigned u = __float_as_uint(f);
  return (u16)((u + 0x7fffu + ((u >> 16) & 1u)) >> 16);
}
// pack two floats to bf16 pair (round-half-up): lo = a, hi = b
DEV unsigned pkbf2(float a, float b) {
  unsigned ua = __float_as_uint(a) + 0x8000u;
  unsigned ub = __float_as_uint(b) + 0x8000u;
  return __builtin_amdgcn_perm(ub, ua, 0x07060302u);
}
DEV bf8v mk4(unsigned a, unsigned b, unsigned c, unsigned d) {
  int4 t = {(int)a, (int)b, (int)c, (int)d};
  bf8v r;
  __builtin_memcpy(&r, &t, 16);
  return r;
}
DEV bf8v ld8(const u16* p) {
  bf8v r;
  __builtin_memcpy(&r, p, 16);
  return r;
}
DEV f4v mfma16(bf8v a, bf8v b, f4v c) {
  return __builtin_amdgcn_mfma_f32_16x16x32_bf16(a, b, c, 0, 0, 0);
}
DEV f16v mfma32(bf8v a, bf8v b, f16v c) {
  return __builtin_amdgcn_mfma_f32_32x32x16_bf16(a, b, c, 0, 0, 0);
}
DEV f16v zero16() {
  f16v r;
#pragma unroll
  for (int i = 0; i < 16; i++) r[i] = 0.f;
  return r;
}

// Assemble B-operand fragment (8 contiguous channels [16*ks+8*hh .. +7] of this
// lane's row) from packed D-layout register array pk[g][w][2] via one
// shfl_xor(32) pair exchange. Loops calling this are fully unrolled, so the
// indices are compile-time constants post-unroll (SROA keeps pk in registers).
// NOTE (r1-r5 probes): permlane variant, 3-buffer prefetch, and group fusion
// all REGRESS this kernel (codegen/register effects dominate); this exact
// structure is a sharp local optimum at 128 arch VGPR + 64 AGPR, 2 waves/SIMD.
// Remaining headroom theory (r5): ~2.9GB/dispatch duplicated weight loads ->
// ~83us L2-broadcast floor; would need block-cooperative LDS weight staging.
#define FRAG_ASM(pk, ks, hh)                                                   \
  ({                                                                           \
    int _g = (ks) >> 1, _lw = 2 * ((ks) & 1);                                  \
    unsigned _A0 = pk[_g][_lw][0], _A1 = pk[_g][_lw][1];                       \
    unsigned _B0 = pk[_g][_lw + 1][0], _B1 = pk[_g][_lw + 1][1];               \
    unsigned _own0 = (hh) ? _B0 : _A0, _own1 = (hh) ? _B1 : _A1;               \
    unsigned _snd0 = (hh) ? _A0 : _B0, _snd1 = (hh) ? _A1 : _B1;               \
    unsigned _o0 = (unsigned)__shfl_xor((int)_snd0, 32, 64);                   \
    unsigned _o1 = (unsigned)__shfl_xor((int)_snd1, 32, 64);                   \
    mk4((hh) ? _o0 : _own0, (hh) ? _o1 : _own1,                                \
        (hh) ? _own0 : _o0, (hh) ? _own1 : _o1);                               \
  })

// ---------------- fused weight swizzle prepass (fp32 -> bf16 fragments) ----------------
// frag[((k>>3)*N + n)*8 + (k&7)] = src[k*N + n]; k >= K zero-filled.
__global__ void swz_all(
    const float* __restrict__ fw1, const float* __restrict__ fw2,
    const float* __restrict__ fwr, const float* __restrict__ ew1,
    const float* __restrict__ ew2, const float* __restrict__ ewr,
    const float* __restrict__ hw, u16* __restrict__ wb, u16* __restrict__ wsh) {
  int b = blockIdx.x;
  if (b >= 560) {  // head_w [d*255+l][96] -> fragments in k-order kp = l*128 + d
    int i = (b - 560) * 256 + threadIdx.x;
    if (i >= KH * PRED) return;
    int kp = i / PRED, n = i - kp * PRED;
    int l = kp >> 7, d = kp & 127;
    wsh[((size_t)(kp >> 3) * PRED + n) * 8 + (kp & 7)] =
        f2bf(hw[(size_t)(d * PNUM + l) * PRED + n]);
    return;
  }
  const float* src; u16* dst; int K, N, Kp;
  if (b < 32)       { src = fw1; dst = wb;          K = 16;  N = 256; Kp = 32; }
  else if (b < 160) { b -= 32;  src = fw2; dst = wb + 8192;  K = 256; N = 128; Kp = 256; }
  else if (b < 176) { b -= 160; src = fwr; dst = wb + 40960; K = 16;  N = 128; Kp = 32; }
  else {
    int e = (b - 176) >> 6; b = (b - 176) & 63;
    int l = e / 3, w = e - 3 * l;
    const float* basep = (w == 0) ? ew1 : (w == 1) ? ew2 : ewr;
    src = basep + (size_t)l * 16384;
    dst = wb + 45056 + e * 16384;
    K = 128; N = 128; Kp = 128;
  }
  int i = b * 256 + threadIdx.x;
  if (i >= Kp * N) return;
  int k = i / N, n = i - k * N;
  u16 v = (k < K) ? f2bf(src[(size_t)k * N + n]) : (u16)0;
  dst[((size_t)(k >> 3) * N + n) * 8 + (k & 7)] = v;
}

// ---------------- K1: fused gather + fp LEMblock + 2 encoder LEMblocks ----------------
// 32x32x16 MFMA, transposed (A=weight, B=act). Each wave owns 32 rows; lane's
// act-row = lane&31. Between-GEMM relayout done IN REGISTERS via shfl_xor(32)
// (no act LDS, no barriers). LDS only stages the final 64x128 output tile.
// EXACT r0 structure (proven 200us).
__global__ __launch_bounds__(128, 2) void k_lem(
    const float* __restrict__ x,
    const u16* __restrict__ ws1, const float* __restrict__ b1,
    const u16* __restrict__ ws2, const u16* __restrict__ wsr,
    const float* __restrict__ b2, const float* __restrict__ br,
    const float* __restrict__ g, const float* __restrict__ be,
    const u16* __restrict__ wse, const float* __restrict__ eb1,
    const float* __restrict__ eb2, const float* __restrict__ ebr,
    const float* __restrict__ eg, const float* __restrict__ ebe,
    u16* __restrict__ zout) {
  __shared__ __align__(16) u16 zst[64 * 132];
  const int t = threadIdx.x;
  const int lane = t & 63, w = t >> 6;  // w: wave 0..1
  const int hh = lane >> 5, r5 = lane & 31;
  const int tile = blockIdx.x;
  const int row = tile * 64 + w * 32 + r5;

  // gather z0: lane holds patch elems [8*hh .. 8*hh+7] of its row (B-frag K=16)
  bf8v azv;
  {
    unsigned R = (unsigned)row;
    unsigned bn = R / 255u;
    unsigned p = R - bn * 255u;
    const float* px = x + (size_t)bn * 2048u + p * 8u + hh * 8;
    float4 v0 = *(const float4*)px;
    float4 v1 = *(const float4*)(px + 4);
    azv = mk4(pkbf2(v0.x, v0.y), pkbf2(v0.z, v0.w),
              pkbf2(v1.x, v1.y), pkbf2(v1.z, v1.w));
  }

  unsigned hpk[8][4][2];  // packed h (256 chans, D-layout halves)
  unsigned zpk[4][4][2];  // packed z (128 chans)

  // ---- GEMM1: h = relu(W1^T z0 + b1), two halves of 128 cols ----
#pragma unroll
  for (int half = 0; half < 2; half++) {
    f16v a[4];
#pragma unroll
    for (int gg = 0; gg < 4; gg++) {
      bf8v wf = ld8(ws1 + ((size_t)(hh * 256 + (half * 4 + gg) * 32 + r5)) * 8);
      a[gg] = mfma32(wf, azv, zero16());
    }
#pragma unroll
    for (int gg = 0; gg < 4; gg++)
#pragma unroll
      for (int wq = 0; wq < 4; wq++) {
        int c0 = (half * 4 + gg) * 32 + wq * 8 + 4 * hh;
        float4 bv = *(const float4*)(b1 + c0);
        float v0 = fmaxf(a[gg][wq * 4 + 0] + bv.x, 0.f);
        float v1 = fmaxf(a[gg][wq * 4 + 1] + bv.y, 0.f);
        float v2 = fmaxf(a[gg][wq * 4 + 2] + bv.z, 0.f);
        float v3 = fmaxf(a[gg][wq * 4 + 3] + bv.w, 0.f);
        hpk[half * 4 + gg][wq][0] = pkbf2(v0, v1);
        hpk[half * 4 + gg][wq][1] = pkbf2(v2, v3);
      }
  }

  // ---- GEMM2: y1 = W2^T h + Wr^T z0 + b2 + br -> LN -> z1 ----
  {
    f16v acc[4];
#pragma unroll
    for (int gg = 0; gg < 4; gg++) {
      bf8v wf = ld8(wsr + ((size_t)(hh * 128 + gg * 32 + r5)) * 8);
      acc[gg] = mfma32(wf, azv, zero16());
    }
    bf8v wq[2][4];
#pragma unroll
    for (int gg = 0; gg < 4; gg++)
      wq[0][gg] = ld8(ws2 + ((size_t)(hh * 128 + gg * 32 + r5)) * 8);
    bf8v bf_cur = FRAG_ASM(hpk, 0, hh);
#pragma unroll
    for (int ks = 0; ks < 16; ks++) {
      int cur = ks & 1;
      if (ks < 15) {
#pragma unroll
        for (int gg = 0; gg < 4; gg++)
          wq[cur ^ 1][gg] =
              ld8(ws2 + ((size_t)((2 * (ks + 1) + hh) * 128 + gg * 32 + r5)) * 8);
        bf8v bf_nxt = FRAG_ASM(hpk, ks + 1, hh);
#pragma unroll
        for (int gg = 0; gg < 4; gg++) acc[gg] = mfma32(wq[cur][gg], bf_cur, acc[gg]);
        bf_cur = bf_nxt;
      } else {
#pragma unroll
        for (int gg = 0; gg < 4; gg++) acc[gg] = mfma32(wq[cur][gg], bf_cur, acc[gg]);
      }
    }
    // bias + LN
    float s = 0.f, s2 = 0.f;
#pragma unroll
    for (int gg = 0; gg < 4; gg++)
#pragma unroll
      for (int wq4 = 0; wq4 < 4; wq4++) {
        int c0 = gg * 32 + wq4 * 8 + 4 * hh;
        float4 bv2 = *(const float4*)(b2 + c0);
        float4 bvr = *(const float4*)(br + c0);
        acc[gg][wq4 * 4 + 0] += bv2.x + bvr.x;
        acc[gg][wq4 * 4 + 1] += bv2.y + bvr.y;
        acc[gg][wq4 * 4 + 2] += bv2.z + bvr.z;
        acc[gg][wq4 * 4 + 3] += bv2.w + bvr.w;
#pragma unroll
        for (int sidx = 0; sidx < 4; sidx++) {
          float v = acc[gg][wq4 * 4 + sidx];
          s += v; s2 += v * v;
        }
      }
    s += __shfl_xor(s, 32, 64); s2 += __shfl_xor(s2, 32, 64);
    float mean = s * (1.f / 128.f);
    float rstd = rsqrtf(s2 * (1.f / 128.f) - mean * mean + 1e-5f);
#pragma unroll
    for (int gg = 0; gg < 4; gg++)
#pragma unroll
      for (int wq4 = 0; wq4 < 4; wq4++) {
        int c0 = gg * 32 + wq4 * 8 + 4 * hh;
        float4 gv = *(const float4*)(g + c0);
        float4 bv = *(const float4*)(be + c0);
        float v0 = (acc[gg][wq4 * 4 + 0] - mean) * rstd * gv.x + bv.x;
        float v1 = (acc[gg][wq4 * 4 + 1] - mean) * rstd * gv.y + bv.y;
        float v2 = (acc[gg][wq4 * 4 + 2] - mean) * rstd * gv.z + bv.z;
        float v3 = (acc[gg][wq4 * 4 + 3] - mean) * rstd * gv.w + bv.w;
        zpk[gg][wq4][0] = pkbf2(v0, v1);
        zpk[gg][wq4][1] = pkbf2(v2, v3);
      }
  }

  // ---- encoder layers ----
#pragma unroll 1
  for (int L = 0; L < 2; L++) {
    const u16* w1p = wse + (size_t)(L * 3 + 0) * 16384;
    const u16* w2p = wse + (size_t)(L * 3 + 1) * 16384;
    const u16* wrp = wse + (size_t)(L * 3 + 2) * 16384;
    unsigned hp2[4][4][2];
    // GEMM-A: h2 = relu(W1^T z + eb1)
    {
      f16v a2[4];
#pragma unroll
      for (int gg = 0; gg < 4; gg++) a2[gg] = zero16();
      bf8v wq[2][4];
#pragma unroll
      for (int gg = 0; gg < 4; gg++)
        wq[0][gg] = ld8(w1p + ((size_t)(hh * 128 + gg * 32 + r5)) * 8);
      bf8v bf_cur = FRAG_ASM(zpk, 0, hh);
#pragma unroll
      for (int ks = 0; ks < 8; ks++) {
        int cur = ks & 1;
        if (ks < 7) {
#pragma unroll
          for (int gg = 0; gg < 4; gg++)
            wq[cur ^ 1][gg] =
                ld8(w1p + ((size_t)((2 * (ks + 1) + hh) * 128 + gg * 32 + r5)) * 8);
          bf8v bf_nxt = FRAG_ASM(zpk, ks + 1, hh);
#pragma unroll
          for (int gg = 0; gg < 4; gg++) a2[gg] = mfma32(wq[cur][gg], bf_cur, a2[gg]);
          bf_cur = bf_nxt;
        } else {
#pragma unroll
          for (int gg = 0; gg < 4; gg++) a2[gg] = mfma32(wq[cur][gg], bf_cur, a2[gg]);
        }
      }
#pragma unroll
      for (int gg = 0; gg < 4; gg++)
#pragma unroll
        for (int wq4 = 0; wq4 < 4; wq4++) {
          int c0 = gg * 32 + wq4 * 8 + 4 * hh;
          float4 bv = *(const float4*)(eb1 + L * 128 + c0);
          float v0 = fmaxf(a2[gg][wq4 * 4 + 0] + bv.x, 0.f);
          float v1 = fmaxf(a2[gg][wq4 * 4 + 1] + bv.y, 0.f);
          float v2 = fmaxf(a2[gg][wq4 * 4 + 2] + bv.z, 0.f);
          float v3 = fmaxf(a2[gg][wq4 * 4 + 3] + bv.w, 0.f);
          hp2[gg][wq4][0] = pkbf2(v0, v1);
          hp2[gg][wq4][1] = pkbf2(v2, v3);
        }
    }
    // GEMM-B: y = W2^T h2 + Wr^T z + biases -> LN
    f16v acc[4];
#pragma unroll
    for (int gg = 0; gg < 4; gg++) acc[gg] = zero16();
    {
      bf8v wq[2][4];
#pragma unroll
      for (int gg = 0; gg < 4; gg++)
        wq[0][gg] = ld8(w2p + ((size_t)(hh * 128 + gg * 32 + r5)) * 8);
      bf8v bf_cur = FRAG_ASM(hp2, 0, hh);
#pragma unroll
      for (int ks = 0; ks < 8; ks++) {
        int cur = ks & 1;
        if (ks < 7) {
#pragma unroll
          for (int gg = 0; gg < 4; gg++)
            wq[cur ^ 1][gg] =
                ld8(w2p + ((size_t)((2 * (ks + 1) + hh) * 128 + gg * 32 + r5)) * 8);
          bf8v bf_nxt = FRAG_ASM(hp2, ks + 1, hh);
#pragma unroll
          for (int gg = 0; gg < 4; gg++) acc[gg] = mfma32(wq[cur][gg], bf_cur, acc[gg]);
          bf_cur = bf_nxt;
        } else {
#pragma unroll
          for (int gg = 0; gg < 4; gg++) acc[gg] = mfma32(wq[cur][gg], bf_cur, acc[gg]);
        }
      }
#pragma unroll
      for (int gg = 0; gg < 4; gg++)
        wq[0][gg] = ld8(wrp + ((size_t)(hh * 128 + gg * 32 + r5)) * 8);
      bf_cur = FRAG_ASM(zpk, 0, hh);
#pragma unroll
      for (int ks = 0; ks < 8; ks++) {
        int cur = ks & 1;
        if (ks < 7) {
#pragma unroll
          for (int gg = 0; gg < 4; gg++)
            wq[cur ^ 1][gg] =
                ld8(wrp + ((size_t)((2 * (ks + 1) + hh) * 128 + gg * 32 + r5)) * 8);
          bf8v bf_nxt = FRAG_ASM(zpk, ks + 1, hh);
#pragma unroll
          for (int gg = 0; gg < 4; gg++) acc[gg] = mfma32(wq[cur][gg], bf_cur, acc[gg]);
          bf_cur = bf_nxt;
        } else {
#pragma unroll
          for (int gg = 0; gg < 4; gg++) acc[gg] = mfma32(wq[cur][gg], bf_cur, acc[gg]);
        }
      }
    }
    float s = 0.f, s2 = 0.f;
#pragma unroll
    for (int gg = 0; gg < 4; gg++)
#pragma unroll
      for (int wq4 = 0; wq4 < 4; wq4++) {
        int c0 = gg * 32 + wq4 * 8 + 4 * hh;
        float4 bv2 = *(const float4*)(eb2 + L * 128 + c0);
        float4 bvr = *(const float4*)(ebr + L * 128 + c0);
        acc[gg][wq4 * 4 + 0] += bv2.x + bvr.x;
        acc[gg][wq4 * 4 + 1] += bv2.y + bvr.y;
        acc[gg][wq4 * 4 + 2] += bv2.z + bvr.z;
        acc[gg][wq4 * 4 + 3] += bv2.w + bvr.w;
#pragma unroll
        for (int sidx = 0; sidx < 4; sidx++) {
          float v = acc[gg][wq4 * 4 + sidx];
          s += v; s2 += v * v;
        }
      }
    s += __shfl_xor(s, 32, 64); s2 += __shfl_xor(s2, 32, 64);
    float mean = s * (1.f / 128.f);
    float rstd = rsqrtf(s2 * (1.f / 128.f) - mean * mean + 1e-5f);
#pragma unroll
    for (int gg = 0; gg < 4; gg++)
#pragma unroll
      for (int wq4 = 0; wq4 < 4; wq4++) {
        int c0 = gg * 32 + wq4 * 8 + 4 * hh;
        float4 gv = *(const float4*)(eg + L * 128 + c0);
        float4 bv = *(const float4*)(ebe + L * 128 + c0);
        float v0 = (acc[gg][wq4 * 4 + 0] - mean) * rstd * gv.x + bv.x;
        float v1 = (acc[gg][wq4 * 4 + 1] - mean) * rstd * gv.y + bv.y;
        float v2 = (acc[gg][wq4 * 4 + 2] - mean) * rstd * gv.z + bv.z;
        float v3 = (acc[gg][wq4 * 4 + 3] - mean) * rstd * gv.w + bv.w;
        unsigned plo = pkbf2(v0, v1), phi = pkbf2(v2, v3);
        if (L == 0) {
          zpk[gg][wq4][0] = plo;
          zpk[gg][wq4][1] = phi;
        } else {
          uint2 pv = {plo, phi};
          *(uint2*)(zst + (w * 32 + r5) * 132 + c0) = pv;
        }
      }
  }

  // per-wave coalesced store of its own 32 rows (same-wave LDS RAW: no barrier)
#pragma unroll
  for (int it = 0; it < 8; it++) {
    int lu = it * 64 + lane;
    int rr = lu >> 4, seg = lu & 15;
    int orow = w * 32 + rr;
    *(uint4*)(zout + ((size_t)tile * 64 + orow) * 128 + seg * 8) =
        *(const uint4*)(zst + orow * 132 + seg * 8);
  }
}

// ---------------- K2: MultiHeadEMA (2-state scan) + residual + silu, IN-PLACE ----------------
// EXACT r0 structure (r5 double-buffer variant regressed ~35us: halved
// blocks/CU via 32KB LDS and the prefetch serialized ahead of the scan).
__global__ __launch_bounds__(128) void k_ema(
    u16* __restrict__ z,
    const float* __restrict__ pdel, const float* __restrict__ palp,
    const float* __restrict__ pbet, const float* __restrict__ pgam,
    const float* __restrict__ pome) {
  __shared__ __align__(16) u16 zc[64 * 128];
  const int t = threadIdx.x;  // channel d
  const int bn = blockIdx.x;
  float p0 = 1.f / (1.f + __expf(-pdel[t * 2 + 0]));
  float p1 = 1.f / (1.f + __expf(-pdel[t * 2 + 1]));
  float q0 = 1.f - p0 / (1.f + __expf(-palp[t * 2 + 0]));
  float q1 = 1.f - p1 / (1.f + __expf(-palp[t * 2 + 1]));
  float w0 = p0 * pbet[t * 2 + 0] * pgam[t * 2 + 0] * EMA_SCALE;
  float w1 = p1 * pbet[t * 2 + 1] * pgam[t * 2 + 1] * EMA_SCALE;
  float om = pome[t];
  float s0 = 0.f, s1 = 0.f;
  u16* slab = z + (size_t)bn * KH;

  for (int ch = 0; ch < 4; ch++) {
    int nrow = (ch < 3) ? 64 : 63;
    int nval = nrow * 128;
    for (int i = t * 8; i < nval; i += 128 * 8)
      *(uint4*)(zc + i) = *(const uint4*)(slab + ch * 8192 + i);
    __syncthreads();
    for (int j0 = 0; j0 < nrow; j0 += 8) {
      float xs[8];
#pragma unroll
      for (int jj = 0; jj < 8; jj++)
        if (j0 + jj < nrow) xs[jj] = bf2f(zc[(j0 + jj) * 128 + t]);
#pragma unroll
      for (int jj = 0; jj < 8; jj++)
        if (j0 + jj < nrow) {
          float xv = xs[jj];
          s0 = q0 * s0 + xv;
          s1 = q1 * s1 + xv;
          float v = w0 * s0 + w1 * s1 + om * xv;
          xs[jj] = v / (1.f + __expf(-v));  // silu
        }
#pragma unroll
      for (int jj = 0; jj < 8; jj++)
        if (j0 + jj < nrow)
          zc[(j0 + jj) * 128 + t] = (u16)((__float_as_uint(xs[jj]) + 0x8000u) >> 16);
    }
    __syncthreads();
    for (int i = t * 8; i < nval; i += 128 * 8)
      *(uint4*)(slab + ch * 8192 + i) = *(const uint4*)(zc + i);
    __syncthreads();
  }
}

// ---------------- K3: head GEMM, fused reduction via fp32 atomics ----------------
// r6: partials go straight into out via atomicAdd (device-scope fp32, native
// on gfx950); ch==0 blocks fold in the bias. Eliminates the 15.5MB part
// write + 15.5MB read and the k_red launch. out starts at 0 (harness memset /
// per-iteration re-poison), so sum over 30 ch-blocks + bias = final value.
__global__ __launch_bounds__(256) void k_head(
    const u16* __restrict__ u, const u16* __restrict__ whs,
    const float* __restrict__ hb, float* __restrict__ out) {
  const int t = threadIdx.x;
  const int lane = t & 63, wid = t >> 6;
  const int quad = lane >> 4, lc = lane & 15;
  const int tile = blockIdx.x;  // 0..20
  const int ch = blockIdx.y;    // 0..29
  const int m0 = tile * 64 + wid * 16;
  const u16* Ab = u + (size_t)(m0 + lc) * KH + (size_t)ch * KPC;
  const int g0 = ch * (KPC / 8);  // base k-group
  f4v acc[6];
#pragma unroll
  for (int n = 0; n < 6; n++) acc[n] = (f4v){0.f, 0.f, 0.f, 0.f};
  bf8v a_nxt = ld8(Ab + quad * 8);
  bf8v b_nxt[6];
#pragma unroll
  for (int n = 0; n < 6; n++)
    b_nxt[n] = ld8(whs + ((size_t)(g0 + quad) * PRED + n * 16 + lc) * 8);
  for (int ks = 0; ks < HITER; ks++) {
    bf8v a_cur = a_nxt;
    bf8v b_cur[6];
#pragma unroll
    for (int n = 0; n < 6; n++) b_cur[n] = b_nxt[n];
    if (ks < HITER - 1) {
      a_nxt = ld8(Ab + (ks + 1) * 32 + quad * 8);
#pragma unroll
      for (int n = 0; n < 6; n++)
        b_nxt[n] = ld8(whs + ((size_t)(g0 + (ks + 1) * 4 + quad) * PRED + n * 16 + lc) * 8);
    }
#pragma unroll
    for (int n = 0; n < 6; n++) acc[n] = mfma16(a_cur, b_cur[n], acc[n]);
  }
#pragma unroll
  for (int n = 0; n < 6; n++) {
    int col = n * 16 + lc;
#pragma unroll
    for (int r = 0; r < 4; r++) {
      float v = acc[n][r];
      if (ch == 0) v += hb[col];  // wave-uniform branch (blockIdx.y)
      atomicAdd(&out[((size_t)(m0 + quad * 4 + r)) * PRED + col], v);
    }
  }
}

// ---------------- host ----------------
extern "C" void kernel_launch(void* const* d_in, const int* in_sizes, int n_in,
                              void* d_out, int out_size, void* d_ws, size_t ws_size,
                              hipStream_t stream) {
  const float* x      = (const float*)d_in[0];
  const float* fp_w1  = (const float*)d_in[1];
  const float* fp_b1  = (const float*)d_in[2];
  const float* fp_w2  = (const float*)d_in[3];
  const float* fp_b2  = (const float*)d_in[4];
  const float* fp_wr  = (const float*)d_in[5];
  const float* fp_br  = (const float*)d_in[6];
  const float* fp_g   = (const float*)d_in[7];
  const float* fp_be  = (const float*)d_in[8];
  const float* enc_w1 = (const float*)d_in[9];
  const float* enc_b1 = (const float*)d_in[10];
  const float* enc_w2 = (const float*)d_in[11];
  const float* enc_b2 = (const float*)d_in[12];
  const float* enc_wr = (const float*)d_in[13];
  const float* enc_br = (const float*)d_in[14];
  const float* enc_g  = (const float*)d_in[15];
  const float* enc_be = (const float*)d_in[16];
  const float* e_del  = (const float*)d_in[17];
  const float* e_alp  = (const float*)d_in[18];
  const float* e_bet  = (const float*)d_in[19];
  const float* e_gam  = (const float*)d_in[20];
  const float* e_om   = (const float*)d_in[21];
  const float* head_w = (const float*)d_in[22];
  const float* head_b = (const float*)d_in[23];

  // ws layout (bytes):
  //   [0, 87736320)             z3 / u  (bf16, [ROWS][128])
  //   [87736320, 103219200)     (unused; former part buffer)
  //   [103219200, ...)          swizzled bf16 weights (~6.6 MB)
  char* base = (char*)d_ws;
  u16* z3 = (u16*)base;
  const size_t EZB = (size_t)ROWS * 128 * 2;        // 87,736,320
  const size_t PARTB = (size_t)CH * BN * PRED * 4;  // 15,482,880 (reserved)
  u16* wb = (u16*)(base + EZB + PARTB);
  // wb offsets (u16): ws1=0(8192), ws2=8192(32768), wsr=40960(4096),
  //                   wse=45056(6*16384), wsh=143360(32640*96)
  u16* ws1 = wb;
  u16* ws2 = wb + 8192;
  u16* wsr = wb + 40960;
  u16* wse = wb + 45056;
  u16* wsh = wb + 143360;

  swz_all<<<560 + (KH * PRED + 255) / 256, 256, 0, stream>>>(
      fp_w1, fp_w2, fp_wr, enc_w1, enc_w2, enc_wr, head_w, wb, wsh);

  k_lem<<<ROWS / 64, 128, 0, stream>>>(x, ws1, fp_b1, ws2, wsr, fp_b2, fp_br, fp_g, fp_be,
                                       wse, enc_b1, enc_b2, enc_br, enc_g, enc_be, z3);
  k_ema<<<BN, 128, 0, stream>>>(z3, e_del, e_alp, e_bet, e_gam, e_om);
  k_head<<<dim3(21, CH), 256, 0, stream>>>(z3, wsh, head_b, (float*)d_out);
}

// Round 7
// 379.080 us; speedup vs baseline: 1.3936x; 1.0362x over previous
//
#include <hip/hip_runtime.h>

typedef unsigned short u16;
typedef short bf8v __attribute__((ext_vector_type(8)));
typedef float f4v __attribute__((ext_vector_type(4)));
typedef float f16v __attribute__((ext_vector_type(16)));

#define DEV static __device__ __forceinline__

constexpr int BB   = 64;
constexpr int NV   = 21;
constexpr int BN   = BB * NV;       // 1344
constexpr int PNUM = 255;
constexpr int D    = 128;
constexpr int PRED = 96;
constexpr int ROWS = BN * PNUM;     // 342720 = 64 * 5355
constexpr int KH   = D * PNUM;      // 32640 head K
constexpr int CH   = 30;            // head K chunks
constexpr int KPC  = KH / CH;       // 1088 = 34*32
constexpr int HITER = KPC / 32;     // 34
constexpr float EMA_SCALE = 0.70710678118654752440f;  // 1/sqrt(2)

DEV float bf2f(u16 h) { return __uint_as_float(((unsigned)h) << 16); }
DEV u16 f2bf(float f) {  // RNE (weight prepass only)
  unsigned u = __float_as_uint(f);
  return (u16)((u + 0x7fffu + ((u >> 16) & 1u)) >> 16);
}
// pack two floats to bf16 pair (round-half-up): lo = a, hi = b
DEV unsigned pkbf2(float a, float b) {
  unsigned ua = __float_as_uint(a) + 0x8000u;
  unsigned ub = __float_as_uint(b) + 0x8000u;
  return __builtin_amdgcn_perm(ub, ua, 0x07060302u);
}
DEV bf8v mk4(unsigned a, unsigned b, unsigned c, unsigned d) {
  int4 t = {(int)a, (int)b, (int)c, (int)d};
  bf8v r;
  __builtin_memcpy(&r, &t, 16);
  return r;
}
DEV bf8v ld8(const u16* p) {
  bf8v r;
  __builtin_memcpy(&r, p, 16);
  return r;
}
DEV f4v mfma16(bf8v a, bf8v b, f4v c) {
  return __builtin_amdgcn_mfma_f32_16x16x32_bf16(a, b, c, 0, 0, 0);
}
DEV f16v mfma32(bf8v a, bf8v b, f16v c) {
  return __builtin_amdgcn_mfma_f32_32x32x16_bf16(a, b, c, 0, 0, 0);
}
DEV f16v zero16() {
  f16v r;
#pragma unroll
  for (int i = 0; i < 16; i++) r[i] = 0.f;
  return r;
}

// Assemble B-operand fragment (8 contiguous channels [16*ks+8*hh .. +7] of this
// lane's row) from packed D-layout register array pk[g][w][2] via one
// shfl_xor(32) pair exchange. Loops calling this are fully unrolled, so the
// indices are compile-time constants post-unroll (SROA keeps pk in registers).
// NOTE (r1-r5 probes): permlane variant, 3-buffer prefetch, and group fusion
// all REGRESS this kernel (codegen/register effects dominate); this exact
// structure is a sharp local optimum at 128 arch VGPR + 64 AGPR, 2 waves/SIMD.
#define FRAG_ASM(pk, ks, hh)                                                   \
  ({                                                                           \
    int _g = (ks) >> 1, _lw = 2 * ((ks) & 1);                                  \
    unsigned _A0 = pk[_g][_lw][0], _A1 = pk[_g][_lw][1];                       \
    unsigned _B0 = pk[_g][_lw + 1][0], _B1 = pk[_g][_lw + 1][1];               \
    unsigned _own0 = (hh) ? _B0 : _A0, _own1 = (hh) ? _B1 : _A1;               \
    unsigned _snd0 = (hh) ? _A0 : _B0, _snd1 = (hh) ? _A1 : _B1;               \
    unsigned _o0 = (unsigned)__shfl_xor((int)_snd0, 32, 64);                   \
    unsigned _o1 = (unsigned)__shfl_xor((int)_snd1, 32, 64);                   \
    mk4((hh) ? _o0 : _own0, (hh) ? _o1 : _own1,                                \
        (hh) ? _own0 : _o0, (hh) ? _own1 : _o1);                               \
  })

// ---------------- fused weight swizzle prepass (fp32 -> bf16 fragments) ----------------
// frag[((k>>3)*N + n)*8 + (k&7)] = src[k*N + n]; k >= K zero-filled.
__global__ void swz_all(
    const float* __restrict__ fw1, const float* __restrict__ fw2,
    const float* __restrict__ fwr, const float* __restrict__ ew1,
    const float* __restrict__ ew2, const float* __restrict__ ewr,
    const float* __restrict__ hw, u16* __restrict__ wb, u16* __restrict__ wsh) {
  int b = blockIdx.x;
  if (b >= 560) {  // head_w [d*255+l][96] -> fragments in k-order kp = l*128 + d
    int i = (b - 560) * 256 + threadIdx.x;
    if (i >= KH * PRED) return;
    int kp = i / PRED, n = i - kp * PRED;
    int l = kp >> 7, d = kp & 127;
    wsh[((size_t)(kp >> 3) * PRED + n) * 8 + (kp & 7)] =
        f2bf(hw[(size_t)(d * PNUM + l) * PRED + n]);
    return;
  }
  const float* src; u16* dst; int K, N, Kp;
  if (b < 32)       { src = fw1; dst = wb;          K = 16;  N = 256; Kp = 32; }
  else if (b < 160) { b -= 32;  src = fw2; dst = wb + 8192;  K = 256; N = 128; Kp = 256; }
  else if (b < 176) { b -= 160; src = fwr; dst = wb + 40960; K = 16;  N = 128; Kp = 32; }
  else {
    int e = (b - 176) >> 6; b = (b - 176) & 63;
    int l = e / 3, w = e - 3 * l;
    const float* basep = (w == 0) ? ew1 : (w == 1) ? ew2 : ewr;
    src = basep + (size_t)l * 16384;
    dst = wb + 45056 + e * 16384;
    K = 128; N = 128; Kp = 128;
  }
  int i = b * 256 + threadIdx.x;
  if (i >= Kp * N) return;
  int k = i / N, n = i - k * N;
  u16 v = (k < K) ? f2bf(src[(size_t)k * N + n]) : (u16)0;
  dst[((size_t)(k >> 3) * N + n) * 8 + (k & 7)] = v;
}

// ---------------- K1: fused gather + fp LEMblock + 2 encoder LEMblocks ----------------
// 32x32x16 MFMA, transposed (A=weight, B=act). Each wave owns 32 rows; lane's
// act-row = lane&31. Between-GEMM relayout done IN REGISTERS via shfl_xor(32)
// (no act LDS, no barriers). LDS only stages the final 64x128 output tile.
// EXACT r0 structure (proven 200us).
__global__ __launch_bounds__(128, 2) void k_lem(
    const float* __restrict__ x,
    const u16* __restrict__ ws1, const float* __restrict__ b1,
    const u16* __restrict__ ws2, const u16* __restrict__ wsr,
    const float* __restrict__ b2, const float* __restrict__ br,
    const float* __restrict__ g, const float* __restrict__ be,
    const u16* __restrict__ wse, const float* __restrict__ eb1,
    const float* __restrict__ eb2, const float* __restrict__ ebr,
    const float* __restrict__ eg, const float* __restrict__ ebe,
    u16* __restrict__ zout) {
  __shared__ __align__(16) u16 zst[64 * 132];
  const int t = threadIdx.x;
  const int lane = t & 63, w = t >> 6;  // w: wave 0..1
  const int hh = lane >> 5, r5 = lane & 31;
  const int tile = blockIdx.x;
  const int row = tile * 64 + w * 32 + r5;

  // gather z0: lane holds patch elems [8*hh .. 8*hh+7] of its row (B-frag K=16)
  bf8v azv;
  {
    unsigned R = (unsigned)row;
    unsigned bn = R / 255u;
    unsigned p = R - bn * 255u;
    const float* px = x + (size_t)bn * 2048u + p * 8u + hh * 8;
    float4 v0 = *(const float4*)px;
    float4 v1 = *(const float4*)(px + 4);
    azv = mk4(pkbf2(v0.x, v0.y), pkbf2(v0.z, v0.w),
              pkbf2(v1.x, v1.y), pkbf2(v1.z, v1.w));
  }

  unsigned hpk[8][4][2];  // packed h (256 chans, D-layout halves)
  unsigned zpk[4][4][2];  // packed z (128 chans)

  // ---- GEMM1: h = relu(W1^T z0 + b1), two halves of 128 cols ----
#pragma unroll
  for (int half = 0; half < 2; half++) {
    f16v a[4];
#pragma unroll
    for (int gg = 0; gg < 4; gg++) {
      bf8v wf = ld8(ws1 + ((size_t)(hh * 256 + (half * 4 + gg) * 32 + r5)) * 8);
      a[gg] = mfma32(wf, azv, zero16());
    }
#pragma unroll
    for (int gg = 0; gg < 4; gg++)
#pragma unroll
      for (int wq = 0; wq < 4; wq++) {
        int c0 = (half * 4 + gg) * 32 + wq * 8 + 4 * hh;
        float4 bv = *(const float4*)(b1 + c0);
        float v0 = fmaxf(a[gg][wq * 4 + 0] + bv.x, 0.f);
        float v1 = fmaxf(a[gg][wq * 4 + 1] + bv.y, 0.f);
        float v2 = fmaxf(a[gg][wq * 4 + 2] + bv.z, 0.f);
        float v3 = fmaxf(a[gg][wq * 4 + 3] + bv.w, 0.f);
        hpk[half * 4 + gg][wq][0] = pkbf2(v0, v1);
        hpk[half * 4 + gg][wq][1] = pkbf2(v2, v3);
      }
  }

  // ---- GEMM2: y1 = W2^T h + Wr^T z0 + b2 + br -> LN -> z1 ----
  {
    f16v acc[4];
#pragma unroll
    for (int gg = 0; gg < 4; gg++) {
      bf8v wf = ld8(wsr + ((size_t)(hh * 128 + gg * 32 + r5)) * 8);
      acc[gg] = mfma32(wf, azv, zero16());
    }
    bf8v wq[2][4];
#pragma unroll
    for (int gg = 0; gg < 4; gg++)
      wq[0][gg] = ld8(ws2 + ((size_t)(hh * 128 + gg * 32 + r5)) * 8);
    bf8v bf_cur = FRAG_ASM(hpk, 0, hh);
#pragma unroll
    for (int ks = 0; ks < 16; ks++) {
      int cur = ks & 1;
      if (ks < 15) {
#pragma unroll
        for (int gg = 0; gg < 4; gg++)
          wq[cur ^ 1][gg] =
              ld8(ws2 + ((size_t)((2 * (ks + 1) + hh) * 128 + gg * 32 + r5)) * 8);
        bf8v bf_nxt = FRAG_ASM(hpk, ks + 1, hh);
#pragma unroll
        for (int gg = 0; gg < 4; gg++) acc[gg] = mfma32(wq[cur][gg], bf_cur, acc[gg]);
        bf_cur = bf_nxt;
      } else {
#pragma unroll
        for (int gg = 0; gg < 4; gg++) acc[gg] = mfma32(wq[cur][gg], bf_cur, acc[gg]);
      }
    }
    // bias + LN
    float s = 0.f, s2 = 0.f;
#pragma unroll
    for (int gg = 0; gg < 4; gg++)
#pragma unroll
      for (int wq4 = 0; wq4 < 4; wq4++) {
        int c0 = gg * 32 + wq4 * 8 + 4 * hh;
        float4 bv2 = *(const float4*)(b2 + c0);
        float4 bvr = *(const float4*)(br + c0);
        acc[gg][wq4 * 4 + 0] += bv2.x + bvr.x;
        acc[gg][wq4 * 4 + 1] += bv2.y + bvr.y;
        acc[gg][wq4 * 4 + 2] += bv2.z + bvr.z;
        acc[gg][wq4 * 4 + 3] += bv2.w + bvr.w;
#pragma unroll
        for (int sidx = 0; sidx < 4; sidx++) {
          float v = acc[gg][wq4 * 4 + sidx];
          s += v; s2 += v * v;
        }
      }
    s += __shfl_xor(s, 32, 64); s2 += __shfl_xor(s2, 32, 64);
    float mean = s * (1.f / 128.f);
    float rstd = rsqrtf(s2 * (1.f / 128.f) - mean * mean + 1e-5f);
#pragma unroll
    for (int gg = 0; gg < 4; gg++)
#pragma unroll
      for (int wq4 = 0; wq4 < 4; wq4++) {
        int c0 = gg * 32 + wq4 * 8 + 4 * hh;
        float4 gv = *(const float4*)(g + c0);
        float4 bv = *(const float4*)(be + c0);
        float v0 = (acc[gg][wq4 * 4 + 0] - mean) * rstd * gv.x + bv.x;
        float v1 = (acc[gg][wq4 * 4 + 1] - mean) * rstd * gv.y + bv.y;
        float v2 = (acc[gg][wq4 * 4 + 2] - mean) * rstd * gv.z + bv.z;
        float v3 = (acc[gg][wq4 * 4 + 3] - mean) * rstd * gv.w + bv.w;
        zpk[gg][wq4][0] = pkbf2(v0, v1);
        zpk[gg][wq4][1] = pkbf2(v2, v3);
      }
  }

  // ---- encoder layers ----
#pragma unroll 1
  for (int L = 0; L < 2; L++) {
    const u16* w1p = wse + (size_t)(L * 3 + 0) * 16384;
    const u16* w2p = wse + (size_t)(L * 3 + 1) * 16384;
    const u16* wrp = wse + (size_t)(L * 3 + 2) * 16384;
    unsigned hp2[4][4][2];
    // GEMM-A: h2 = relu(W1^T z + eb1)
    {
      f16v a2[4];
#pragma unroll
      for (int gg = 0; gg < 4; gg++) a2[gg] = zero16();
      bf8v wq[2][4];
#pragma unroll
      for (int gg = 0; gg < 4; gg++)
        wq[0][gg] = ld8(w1p + ((size_t)(hh * 128 + gg * 32 + r5)) * 8);
      bf8v bf_cur = FRAG_ASM(zpk, 0, hh);
#pragma unroll
      for (int ks = 0; ks < 8; ks++) {
        int cur = ks & 1;
        if (ks < 7) {
#pragma unroll
          for (int gg = 0; gg < 4; gg++)
            wq[cur ^ 1][gg] =
                ld8(w1p + ((size_t)((2 * (ks + 1) + hh) * 128 + gg * 32 + r5)) * 8);
          bf8v bf_nxt = FRAG_ASM(zpk, ks + 1, hh);
#pragma unroll
          for (int gg = 0; gg < 4; gg++) a2[gg] = mfma32(wq[cur][gg], bf_cur, a2[gg]);
          bf_cur = bf_nxt;
        } else {
#pragma unroll
          for (int gg = 0; gg < 4; gg++) a2[gg] = mfma32(wq[cur][gg], bf_cur, a2[gg]);
        }
      }
#pragma unroll
      for (int gg = 0; gg < 4; gg++)
#pragma unroll
        for (int wq4 = 0; wq4 < 4; wq4++) {
          int c0 = gg * 32 + wq4 * 8 + 4 * hh;
          float4 bv = *(const float4*)(eb1 + L * 128 + c0);
          float v0 = fmaxf(a2[gg][wq4 * 4 + 0] + bv.x, 0.f);
          float v1 = fmaxf(a2[gg][wq4 * 4 + 1] + bv.y, 0.f);
          float v2 = fmaxf(a2[gg][wq4 * 4 + 2] + bv.z, 0.f);
          float v3 = fmaxf(a2[gg][wq4 * 4 + 3] + bv.w, 0.f);
          hp2[gg][wq4][0] = pkbf2(v0, v1);
          hp2[gg][wq4][1] = pkbf2(v2, v3);
        }
    }
    // GEMM-B: y = W2^T h2 + Wr^T z + biases -> LN
    f16v acc[4];
#pragma unroll
    for (int gg = 0; gg < 4; gg++) acc[gg] = zero16();
    {
      bf8v wq[2][4];
#pragma unroll
      for (int gg = 0; gg < 4; gg++)
        wq[0][gg] = ld8(w2p + ((size_t)(hh * 128 + gg * 32 + r5)) * 8);
      bf8v bf_cur = FRAG_ASM(hp2, 0, hh);
#pragma unroll
      for (int ks = 0; ks < 8; ks++) {
        int cur = ks & 1;
        if (ks < 7) {
#pragma unroll
          for (int gg = 0; gg < 4; gg++)
            wq[cur ^ 1][gg] =
                ld8(w2p + ((size_t)((2 * (ks + 1) + hh) * 128 + gg * 32 + r5)) * 8);
          bf8v bf_nxt = FRAG_ASM(hp2, ks + 1, hh);
#pragma unroll
          for (int gg = 0; gg < 4; gg++) acc[gg] = mfma32(wq[cur][gg], bf_cur, acc[gg]);
          bf_cur = bf_nxt;
        } else {
#pragma unroll
          for (int gg = 0; gg < 4; gg++) acc[gg] = mfma32(wq[cur][gg], bf_cur, acc[gg]);
        }
      }
#pragma unroll
      for (int gg = 0; gg < 4; gg++)
        wq[0][gg] = ld8(wrp + ((size_t)(hh * 128 + gg * 32 + r5)) * 8);
      bf_cur = FRAG_ASM(zpk, 0, hh);
#pragma unroll
      for (int ks = 0; ks < 8; ks++) {
        int cur = ks & 1;
        if (ks < 7) {
#pragma unroll
          for (int gg = 0; gg < 4; gg++)
            wq[cur ^ 1][gg] =
                ld8(wrp + ((size_t)((2 * (ks + 1) + hh) * 128 + gg * 32 + r5)) * 8);
          bf8v bf_nxt = FRAG_ASM(zpk, ks + 1, hh);
#pragma unroll
          for (int gg = 0; gg < 4; gg++) acc[gg] = mfma32(wq[cur][gg], bf_cur, acc[gg]);
          bf_cur = bf_nxt;
        } else {
#pragma unroll
          for (int gg = 0; gg < 4; gg++) acc[gg] = mfma32(wq[cur][gg], bf_cur, acc[gg]);
        }
      }
    }
    float s = 0.f, s2 = 0.f;
#pragma unroll
    for (int gg = 0; gg < 4; gg++)
#pragma unroll
      for (int wq4 = 0; wq4 < 4; wq4++) {
        int c0 = gg * 32 + wq4 * 8 + 4 * hh;
        float4 bv2 = *(const float4*)(eb2 + L * 128 + c0);
        float4 bvr = *(const float4*)(ebr + L * 128 + c0);
        acc[gg][wq4 * 4 + 0] += bv2.x + bvr.x;
        acc[gg][wq4 * 4 + 1] += bv2.y + bvr.y;
        acc[gg][wq4 * 4 + 2] += bv2.z + bvr.z;
        acc[gg][wq4 * 4 + 3] += bv2.w + bvr.w;
#pragma unroll
        for (int sidx = 0; sidx < 4; sidx++) {
          float v = acc[gg][wq4 * 4 + sidx];
          s += v; s2 += v * v;
        }
      }
    s += __shfl_xor(s, 32, 64); s2 += __shfl_xor(s2, 32, 64);
    float mean = s * (1.f / 128.f);
    float rstd = rsqrtf(s2 * (1.f / 128.f) - mean * mean + 1e-5f);
#pragma unroll
    for (int gg = 0; gg < 4; gg++)
#pragma unroll
      for (int wq4 = 0; wq4 < 4; wq4++) {
        int c0 = gg * 32 + wq4 * 8 + 4 * hh;
        float4 gv = *(const float4*)(eg + L * 128 + c0);
        float4 bv = *(const float4*)(ebe + L * 128 + c0);
        float v0 = (acc[gg][wq4 * 4 + 0] - mean) * rstd * gv.x + bv.x;
        float v1 = (acc[gg][wq4 * 4 + 1] - mean) * rstd * gv.y + bv.y;
        float v2 = (acc[gg][wq4 * 4 + 2] - mean) * rstd * gv.z + bv.z;
        float v3 = (acc[gg][wq4 * 4 + 3] - mean) * rstd * gv.w + bv.w;
        unsigned plo = pkbf2(v0, v1), phi = pkbf2(v2, v3);
        if (L == 0) {
          zpk[gg][wq4][0] = plo;
          zpk[gg][wq4][1] = phi;
        } else {
          uint2 pv = {plo, phi};
          *(uint2*)(zst + (w * 32 + r5) * 132 + c0) = pv;
        }
      }
  }

  // per-wave coalesced store of its own 32 rows (same-wave LDS RAW: no barrier)
#pragma unroll
  for (int it = 0; it < 8; it++) {
    int lu = it * 64 + lane;
    int rr = lu >> 4, seg = lu & 15;
    int orow = w * 32 + rr;
    *(uint4*)(zout + ((size_t)tile * 64 + orow) * 128 + seg * 8) =
        *(const uint4*)(zst + orow * 132 + seg * 8);
  }
}

// ---------------- K2: MultiHeadEMA (2-state scan) + residual + silu, IN-PLACE ----------------
// r7: register-resident column scan, NO LDS, NO barriers. For fixed row j,
// threads t=0..127 touch consecutive u16 -> 2B/lane accesses are coalesced
// (128B per wave-instr) both for loads and stores, same as the old LDS path
// but without the LDS round-trip and 12 __syncthreads per block. 8-row groups
// keep 8 loads in flight; TLP (~10 waves/CU) hides the rest.
__global__ __launch_bounds__(128) void k_ema(
    u16* __restrict__ z,
    const float* __restrict__ pdel, const float* __restrict__ palp,
    const float* __restrict__ pbet, const float* __restrict__ pgam,
    const float* __restrict__ pome) {
  const int t = threadIdx.x;  // channel d
  const int bn = blockIdx.x;
  float p0 = 1.f / (1.f + __expf(-pdel[t * 2 + 0]));
  float p1 = 1.f / (1.f + __expf(-pdel[t * 2 + 1]));
  float q0 = 1.f - p0 / (1.f + __expf(-palp[t * 2 + 0]));
  float q1 = 1.f - p1 / (1.f + __expf(-palp[t * 2 + 1]));
  float w0 = p0 * pbet[t * 2 + 0] * pgam[t * 2 + 0] * EMA_SCALE;
  float w1 = p1 * pbet[t * 2 + 1] * pgam[t * 2 + 1] * EMA_SCALE;
  float om = pome[t];
  float s0 = 0.f, s1 = 0.f;
  u16* col = z + (size_t)bn * KH + t;  // this thread's channel column

  for (int j0 = 0; j0 < PNUM; j0 += 8) {
    int nr = (PNUM - j0 < 8) ? (PNUM - j0) : 8;  // uniform across threads
    float xs[8];
#pragma unroll
    for (int jj = 0; jj < 8; jj++)
      if (jj < nr) xs[jj] = bf2f(col[(size_t)(j0 + jj) * 128]);
#pragma unroll
    for (int jj = 0; jj < 8; jj++)
      if (jj < nr) {
        float xv = xs[jj];
        s0 = q0 * s0 + xv;
        s1 = q1 * s1 + xv;
        float v = w0 * s0 + w1 * s1 + om * xv;
        xs[jj] = v / (1.f + __expf(-v));  // silu
      }
#pragma unroll
    for (int jj = 0; jj < 8; jj++)
      if (jj < nr)
        col[(size_t)(j0 + jj) * 128] =
            (u16)((__float_as_uint(xs[jj]) + 0x8000u) >> 16);
  }
}

// ---------------- K3: head GEMM partials (K split into 30 chunks of 1088) ----------------
// EXACT r0 structure (r6 atomic-fusion variant was +9us: 30-way fp32 atomic
// contention at L2 beats the 15.5MB part round-trip it saved).
__global__ __launch_bounds__(256) void k_head(
    const u16* __restrict__ u, const u16* __restrict__ whs, float* __restrict__ part) {
  const int t = threadIdx.x;
  const int lane = t & 63, wid = t >> 6;
  const int quad = lane >> 4, lc = lane & 15;
  const int tile = blockIdx.x;  // 0..20
  const int ch = blockIdx.y;    // 0..29
  const int m0 = tile * 64 + wid * 16;
  const u16* Ab = u + (size_t)(m0 + lc) * KH + (size_t)ch * KPC;
  const int g0 = ch * (KPC / 8);  // base k-group
  f4v acc[6];
#pragma unroll
  for (int n = 0; n < 6; n++) acc[n] = (f4v){0.f, 0.f, 0.f, 0.f};
  bf8v a_nxt = ld8(Ab + quad * 8);
  bf8v b_nxt[6];
#pragma unroll
  for (int n = 0; n < 6; n++)
    b_nxt[n] = ld8(whs + ((size_t)(g0 + quad) * PRED + n * 16 + lc) * 8);
  for (int ks = 0; ks < HITER; ks++) {
    bf8v a_cur = a_nxt;
    bf8v b_cur[6];
#pragma unroll
    for (int n = 0; n < 6; n++) b_cur[n] = b_nxt[n];
    if (ks < HITER - 1) {
      a_nxt = ld8(Ab + (ks + 1) * 32 + quad * 8);
#pragma unroll
      for (int n = 0; n < 6; n++)
        b_nxt[n] = ld8(whs + ((size_t)(g0 + (ks + 1) * 4 + quad) * PRED + n * 16 + lc) * 8);
    }
#pragma unroll
    for (int n = 0; n < 6; n++) acc[n] = mfma16(a_cur, b_cur[n], acc[n]);
  }
#pragma unroll
  for (int n = 0; n < 6; n++) {
    int col = n * 16 + lc;
#pragma unroll
    for (int r = 0; r < 4; r++)
      part[((size_t)ch * BN + m0 + quad * 4 + r) * PRED + col] = acc[n][r];
  }
}

// ---------------- K4: reduce partials + bias -> fp32 out ----------------
__global__ __launch_bounds__(256) void k_red(
    const float* __restrict__ part, const float* __restrict__ hb, float* __restrict__ out) {
  int i = blockIdx.x * 256 + threadIdx.x;
  if (i >= BN * PRED) return;
  int row = i / PRED, col = i - row * PRED;
  float s = hb[col];
#pragma unroll 5
  for (int c = 0; c < CH; c++) s += part[((size_t)c * BN + row) * PRED + col];
  out[i] = s;
}

// ---------------- host ----------------
extern "C" void kernel_launch(void* const* d_in, const int* in_sizes, int n_in,
                              void* d_out, int out_size, void* d_ws, size_t ws_size,
                              hipStream_t stream) {
  const float* x      = (const float*)d_in[0];
  const float* fp_w1  = (const float*)d_in[1];
  const float* fp_b1  = (const float*)d_in[2];
  const float* fp_w2  = (const float*)d_in[3];
  const float* fp_b2  = (const float*)d_in[4];
  const float* fp_wr  = (const float*)d_in[5];
  const float* fp_br  = (const float*)d_in[6];
  const float* fp_g   = (const float*)d_in[7];
  const float* fp_be  = (const float*)d_in[8];
  const float* enc_w1 = (const float*)d_in[9];
  const float* enc_b1 = (const float*)d_in[10];
  const float* enc_w2 = (const float*)d_in[11];
  const float* enc_b2 = (const float*)d_in[12];
  const float* enc_wr = (const float*)d_in[13];
  const float* enc_br = (const float*)d_in[14];
  const float* enc_g  = (const float*)d_in[15];
  const float* enc_be = (const float*)d_in[16];
  const float* e_del  = (const float*)d_in[17];
  const float* e_alp  = (const float*)d_in[18];
  const float* e_bet  = (const float*)d_in[19];
  const float* e_gam  = (const float*)d_in[20];
  const float* e_om   = (const float*)d_in[21];
  const float* head_w = (const float*)d_in[22];
  const float* head_b = (const float*)d_in[23];

  // ws layout (bytes):
  //   [0, 87736320)             z3 / u  (bf16, [ROWS][128])
  //   [87736320, 103219200)     part    (fp32, [30][1344][96])
  //   [103219200, ...)          swizzled bf16 weights (~6.6 MB)
  char* base = (char*)d_ws;
  u16* z3 = (u16*)base;
  const size_t EZB = (size_t)ROWS * 128 * 2;        // 87,736,320
  float* part = (float*)(base + EZB);
  const size_t PARTB = (size_t)CH * BN * PRED * 4;  // 15,482,880
  u16* wb = (u16*)(base + EZB + PARTB);
  // wb offsets (u16): ws1=0(8192), ws2=8192(32768), wsr=40960(4096),
  //                   wse=45056(6*16384), wsh=143360(32640*96)
  u16* ws1 = wb;
  u16* ws2 = wb + 8192;
  u16* wsr = wb + 40960;
  u16* wse = wb + 45056;
  u16* wsh = wb + 143360;

  swz_all<<<560 + (KH * PRED + 255) / 256, 256, 0, stream>>>(
      fp_w1, fp_w2, fp_wr, enc_w1, enc_w2, enc_wr, head_w, wb, wsh);

  k_lem<<<ROWS / 64, 128, 0, stream>>>(x, ws1, fp_b1, ws2, wsr, fp_b2, fp_br, fp_g, fp_be,
                                       wse, enc_b1, enc_b2, enc_br, enc_g, enc_be, z3);
  k_ema<<<BN, 128, 0, stream>>>(z3, e_del, e_alp, e_bet, e_gam, e_om);
  k_head<<<dim3(21, CH), 256, 0, stream>>>(z3, wsh, part);
  k_red<<<(BN * PRED + 255) / 256, 256, 0, stream>>>(part, head_b, (float*)d_out);
}